// Round 1
// baseline (6209.809 us; speedup 1.0000x reference)
//
#include <hip/hip_runtime.h>
#include <math.h>

#define B_  1024
#define N_  16
#define I_  256
#define H_  1024
#define H3_ 3072

// ---------------------------------------------------------------------------
// Precompute t_gate (N,B) and idx_seq (B,N)
// ---------------------------------------------------------------------------
__global__ void precompute_kernel(const float* __restrict__ phis,
                                  float* __restrict__ tg,
                                  int* __restrict__ idx)
{
    int b = blockIdx.x * blockDim.x + threadIdx.x;
    if (b >= B_) return;
    tg[b] = 1.0f;
    for (int t = 1; t < N_; ++t)
        tg[t * B_ + b] = phis[(size_t)b * N_ * N_ + t * N_ + (t - 1)];
    for (int t = 0; t < N_; ++t) {
        float ns = 0.f;
        for (int k = 0; k < N_; ++k) ns += phis[(size_t)b * N_ * N_ + t * N_ + k];
        int nsi = (int)(ns + 0.5f);
        idx[b * N_ + t] = (nsi + t - 1) % N_;
    }
}

// ---------------------------------------------------------------------------
// Register-tiled fp32 GEMM: C[M,N] = A[M,K] @ op(B) + bias
// TRANSB=true : op(B)[k,n] = B[n*ldb + k]  (weights stored (N,K) row-major)
// TRANSB=false: op(B)[k,n] = B[k*ldb + n]
// BM=BN=64, BK=16, 256 threads, 4x4 per thread. M%64==0, N%64==0, K%16==0.
// ---------------------------------------------------------------------------
#define BM 64
#define BN 64
#define BK 16

template <bool TRANSB>
__global__ __launch_bounds__(256) void gemm_kernel(
    const float* __restrict__ A, int lda,
    const float* __restrict__ Bm, int ldb,
    const float* __restrict__ bias,
    float* __restrict__ C, int ldc,
    int M, int N, int K)
{
    __shared__ float As[BK][BM];
    __shared__ float Bs[BK][BN];

    const int tid = threadIdx.x;
    const int tx  = tid & 15;
    const int ty  = tid >> 4;
    const int n0  = blockIdx.x * BN;
    const int m0  = blockIdx.y * BM;

    float acc[4][4];
#pragma unroll
    for (int i = 0; i < 4; ++i)
#pragma unroll
        for (int j = 0; j < 4; ++j) acc[i][j] = 0.f;

    for (int k0 = 0; k0 < K; k0 += BK) {
        // load A tile: 64 rows x 16 cols, float4 along K
        {
            int row = tid >> 2;
            int kk  = (tid & 3) * 4;
            float4 a4 = *reinterpret_cast<const float4*>(&A[(size_t)(m0 + row) * lda + k0 + kk]);
            As[kk + 0][row] = a4.x;
            As[kk + 1][row] = a4.y;
            As[kk + 2][row] = a4.z;
            As[kk + 3][row] = a4.w;
        }
        // load B tile
        if (TRANSB) {
            int n  = tid >> 2;
            int kk = (tid & 3) * 4;
            float4 b4 = *reinterpret_cast<const float4*>(&Bm[(size_t)(n0 + n) * ldb + k0 + kk]);
            Bs[kk + 0][n] = b4.x;
            Bs[kk + 1][n] = b4.y;
            Bs[kk + 2][n] = b4.z;
            Bs[kk + 3][n] = b4.w;
        } else {
            int k  = tid >> 4;
            int nn = (tid & 15) * 4;
            float4 b4 = *reinterpret_cast<const float4*>(&Bm[(size_t)(k0 + k) * ldb + n0 + nn]);
            *reinterpret_cast<float4*>(&Bs[k][nn]) = b4;
        }
        __syncthreads();

#pragma unroll
        for (int k = 0; k < BK; ++k) {
            float4 a4 = *reinterpret_cast<const float4*>(&As[k][ty * 4]);
            float4 b4 = *reinterpret_cast<const float4*>(&Bs[k][tx * 4]);
            float av[4] = {a4.x, a4.y, a4.z, a4.w};
            float bv[4] = {b4.x, b4.y, b4.z, b4.w};
#pragma unroll
            for (int i = 0; i < 4; ++i)
#pragma unroll
                for (int j = 0; j < 4; ++j) acc[i][j] += av[i] * bv[j];
        }
        __syncthreads();
    }

#pragma unroll
    for (int i = 0; i < 4; ++i) {
        int m = m0 + ty * 4 + i;
        int n = n0 + tx * 4;
        float4 o;
        o.x = acc[i][0]; o.y = acc[i][1]; o.z = acc[i][2]; o.w = acc[i][3];
        if (bias) {
            o.x += bias[n + 0]; o.y += bias[n + 1]; o.z += bias[n + 2]; o.w += bias[n + 3];
        }
        *reinterpret_cast<float4*>(&C[(size_t)m * ldc + n]) = o;
    }
}

// ---------------------------------------------------------------------------
// Elementwise kernels
// ---------------------------------------------------------------------------
__global__ void scale_h_kernel(float* __restrict__ h, const float* __restrict__ tg)
{
    int i = blockIdx.x * blockDim.x + threadIdx.x;   // B*H
    int b = i >> 10;
    h[i] *= tg[b];
}

__global__ void gru_elem_kernel(const float* __restrict__ gi,
                                const float* __restrict__ gh,
                                float* __restrict__ h,
                                float* __restrict__ he_t)   // nullable, = he + t*H_
{
    int i = blockIdx.x * blockDim.x + threadIdx.x;   // B*H
    int b = i >> 10;
    int j = i & (H_ - 1);
    size_t base = (size_t)b * H3_;
    float ir = gi[base + j], iz = gi[base + H_ + j], ig = gi[base + 2 * H_ + j];
    float hr = gh[base + j], hz = gh[base + H_ + j], hg = gh[base + 2 * H_ + j];
    float r = 1.f / (1.f + expf(-(ir + hr)));
    float z = 1.f / (1.f + expf(-(iz + hz)));
    float g = tanhf(ig + r * hg);
    float hn = (1.f - z) * g + z * h[i];
    h[i] = hn;
    if (he_t) he_t[(size_t)b * N_ * H_ + j] = hn;
}

__global__ void init_hidden_kernel(float* __restrict__ h,
                                   const float* __restrict__ he,
                                   const int* __restrict__ idx)  // idx_seq[:,0] via idx[b*N_]
{
    int i = blockIdx.x * blockDim.x + threadIdx.x;   // B*H
    int b = i >> 10;
    int j = i & (H_ - 1);
    h[i] = he[(size_t)b * N_ * H_ + (size_t)idx[b * N_] * H_ + j];
}

__global__ void init_input_kernel(float* __restrict__ inp, const float* __restrict__ tok)
{
    int i = blockIdx.x * blockDim.x + threadIdx.x;   // B*I
    inp[i] = tok[i & (I_ - 1)];
}

__global__ void mix_hidden_kernel(float* __restrict__ h,
                                  const float* __restrict__ he,
                                  const int* __restrict__ idx,   // = idx_base + t
                                  const float* __restrict__ tg)  // = tg + t*B_
{
    int i = blockIdx.x * blockDim.x + threadIdx.x;   // B*H
    int b = i >> 10;
    int j = i & (H_ - 1);
    float t = tg[b];
    float ih = he[(size_t)b * N_ * H_ + (size_t)idx[b * N_] * H_ + j];
    h[i] = t * h[i] + (1.f - t) * ih;
}

__global__ void mix_input_kernel(float* __restrict__ inp,
                                 const float* __restrict__ tok,
                                 const float* __restrict__ tg)
{
    int i = blockIdx.x * blockDim.x + threadIdx.x;   // B*I
    int b = i >> 8;
    float t = tg[b];
    inp[i] = t * inp[i] + (1.f - t) * tok[i & (I_ - 1)];
}

// ---------------------------------------------------------------------------
// Attention step: u = tanh(W1xe + hW2) @ v ; masked softmax ; inp = attn @ input
// One block per batch row b. 256 threads.
// ---------------------------------------------------------------------------
__global__ __launch_bounds__(256) void attn_kernel(
    const float* __restrict__ w1xe,   // (B,N,H)
    const float* __restrict__ hw2,    // (B,H)
    const float* __restrict__ v,      // (H)
    const float* __restrict__ phis,   // (B,N,N)
    const float* __restrict__ input,  // (B,N,I)
    float* __restrict__ out,          // (B,N,N)
    float* __restrict__ inp_step,     // (B,I)
    int t)
{
    int b   = blockIdx.x;
    int tid = threadIdx.x;
    __shared__ float hw2s[H_];
    __shared__ float vs[H_];
    __shared__ float un[N_];
    __shared__ float attns[N_];
    __shared__ float red[4];

    for (int k = tid; k < H_; k += 256) {
        hw2s[k] = hw2[(size_t)b * H_ + k];
        vs[k]   = v[k];
    }
    __syncthreads();

    for (int n = 0; n < N_; ++n) {
        const float* wrow = w1xe + ((size_t)(b * N_ + n)) * H_;
        float s = 0.f;
        for (int k = tid; k < H_; k += 256)
            s += tanhf(wrow[k] + hw2s[k]) * vs[k];
        for (int off = 32; off; off >>= 1) s += __shfl_down(s, off, 64);
        if ((tid & 63) == 0) red[tid >> 6] = s;
        __syncthreads();
        if (tid == 0) un[n] = red[0] + red[1] + red[2] + red[3];
        __syncthreads();
    }

    if (tid == 0) {
        float mk[N_], um[N_], e[N_];
        float m = -1e30f;
        for (int n = 0; n < N_; ++n) {
            mk[n] = phis[(size_t)b * N_ * N_ + t * N_ + n];
            um[n] = un[n] * mk[n];
            m = fmaxf(m, um[n]);
        }
        float ssum = 0.f;
        for (int n = 0; n < N_; ++n) { e[n] = expf(um[n] - m) * mk[n]; ssum += e[n]; }
        float inv = 1.f / ssum;
        for (int n = 0; n < N_; ++n) {
            float a = e[n] * inv;
            attns[n] = a;
            out[(size_t)b * N_ * N_ + t * N_ + n] = a;
        }
    }
    __syncthreads();

    {
        int i = tid;   // I_ == 256 == blockDim
        float acc = 0.f;
        for (int n = 0; n < N_; ++n)
            acc += attns[n] * input[((size_t)b * N_ + n) * I_ + i];
        inp_step[(size_t)b * I_ + i] = acc;
    }
}

// ---------------------------------------------------------------------------
// Launcher
// ---------------------------------------------------------------------------
extern "C" void kernel_launch(void* const* d_in, const int* in_sizes, int n_in,
                              void* d_out, int out_size, void* d_ws, size_t ws_size,
                              hipStream_t stream)
{
    const float* input      = (const float*)d_in[0];
    const float* phis       = (const float*)d_in[1];
    const float* init_token = (const float*)d_in[2];
    const float* W1         = (const float*)d_in[3];
    const float* W2         = (const float*)d_in[4];
    const float* v          = (const float*)d_in[5];
    const float* Wih_e      = (const float*)d_in[6];
    const float* Whh_e      = (const float*)d_in[7];
    const float* bih_e      = (const float*)d_in[8];
    const float* bhh_e      = (const float*)d_in[9];
    const float* Wih_d      = (const float*)d_in[10];
    const float* Whh_d      = (const float*)d_in[11];
    const float* bih_d      = (const float*)d_in[12];
    const float* bhh_d      = (const float*)d_in[13];
    float* out = (float*)d_out;

    char* p = (char*)d_ws;
    float* he   = (float*)p; p += (size_t)B_ * N_ * H_ * 4;   // 64 MB
    float* w1xe = (float*)p; p += (size_t)B_ * N_ * H_ * 4;   // 64 MB
    float* h    = (float*)p; p += (size_t)B_ * H_ * 4;        //  4 MB
    float* hw2  = (float*)p; p += (size_t)B_ * H_ * 4;        //  4 MB
    float* gi   = (float*)p; p += (size_t)B_ * H3_ * 4;       // 12 MB
    float* gh   = (float*)p; p += (size_t)B_ * H3_ * 4;       // 12 MB
    float* inp  = (float*)p; p += (size_t)B_ * I_ * 4;        //  1 MB
    float* tg   = (float*)p; p += (size_t)N_ * B_ * 4;
    int*   idx  = (int*)p;   p += (size_t)B_ * N_ * 4;

    const int BHBLK = (B_ * H_) / 256;   // 4096
    const int BIBLK = (B_ * I_) / 256;   // 1024

    // precompute gates / indices
    precompute_kernel<<<4, 256, 0, stream>>>(phis, tg, idx);

    // ---------------- encoder ----------------
    hipMemsetAsync(h, 0, (size_t)B_ * H_ * 4, stream);
    for (int t = 0; t < N_; ++t) {
        scale_h_kernel<<<BHBLK, 256, 0, stream>>>(h, tg + (size_t)t * B_);
        gemm_kernel<true><<<dim3(H3_ / BN, B_ / BM), 256, 0, stream>>>(
            input + (size_t)t * I_, N_ * I_, Wih_e, I_, bih_e, gi, H3_, B_, H3_, I_);
        gemm_kernel<true><<<dim3(H3_ / BN, B_ / BM), 256, 0, stream>>>(
            h, H_, Whh_e, H_, bhh_e, gh, H3_, B_, H3_, H_);
        gru_elem_kernel<<<BHBLK, 256, 0, stream>>>(gi, gh, h, he + (size_t)t * H_);
    }

    // ---------------- W1xe = he @ W1 ----------------
    gemm_kernel<false><<<dim3(H_ / BN, (B_ * N_) / BM), 256, 0, stream>>>(
        he, H_, W1, H_, nullptr, w1xe, H_, B_ * N_, H_, H_);

    // ---------------- decoder ----------------
    init_hidden_kernel<<<BHBLK, 256, 0, stream>>>(h, he, idx);
    init_input_kernel<<<BIBLK, 256, 0, stream>>>(inp, init_token);
    for (int t = 0; t < N_; ++t) {
        mix_hidden_kernel<<<BHBLK, 256, 0, stream>>>(h, he, idx + t, tg + (size_t)t * B_);
        mix_input_kernel<<<BIBLK, 256, 0, stream>>>(inp, init_token, tg + (size_t)t * B_);
        gemm_kernel<true><<<dim3(H3_ / BN, B_ / BM), 256, 0, stream>>>(
            inp, I_, Wih_d, I_, bih_d, gi, H3_, B_, H3_, I_);
        gemm_kernel<true><<<dim3(H3_ / BN, B_ / BM), 256, 0, stream>>>(
            h, H_, Whh_d, H_, bhh_d, gh, H3_, B_, H3_, H_);
        gru_elem_kernel<<<BHBLK, 256, 0, stream>>>(gi, gh, h, nullptr);
        gemm_kernel<false><<<dim3(H_ / BN, B_ / BM), 256, 0, stream>>>(
            h, H_, W2, H_, nullptr, hw2, H_, B_, H_, H_);
        attn_kernel<<<B_, 256, 0, stream>>>(w1xe, hw2, v, phis, input, out, inp, t);
    }
}

// Round 3
// 2538.426 us; speedup vs baseline: 2.4463x; 2.4463x over previous
//
#include <hip/hip_runtime.h>
#include <math.h>

#define B_  1024
#define N_  16
#define I_  256
#define H_  1024
#define H3_ 3072

typedef _Float16 f16;
typedef _Float16 f16x4 __attribute__((ext_vector_type(4)));
typedef _Float16 f16x8 __attribute__((ext_vector_type(8)));
typedef float    f32x4 __attribute__((ext_vector_type(4)));

// ---------------------------------------------------------------------------
// Precompute t_gate (17,B) and idx_seq (B,N)
// ---------------------------------------------------------------------------
__global__ void precompute_kernel(const float* __restrict__ phis,
                                  float* __restrict__ tg,
                                  int* __restrict__ idx)
{
    int b = blockIdx.x * blockDim.x + threadIdx.x;
    if (b >= B_) return;
    tg[b] = 1.0f;
    for (int t = 1; t < N_; ++t)
        tg[t * B_ + b] = phis[(size_t)b * N_ * N_ + t * N_ + (t - 1)];
    tg[16 * B_ + b] = 0.0f;   // sentinel (hs after last encoder step is unused)
    for (int t = 0; t < N_; ++t) {
        float ns = 0.f;
        for (int k = 0; k < N_; ++k) ns += phis[(size_t)b * N_ * N_ + t * N_ + k];
        int nsi = (int)(ns + 0.5f);
        idx[b * N_ + t] = (nsi + t - 1) % N_;
    }
}

// ---------------------------------------------------------------------------
// Casts
// ---------------------------------------------------------------------------
__global__ void cast_kernel(const float* __restrict__ in, f16* __restrict__ out, int n)
{
    int i = blockIdx.x * blockDim.x + threadIdx.x;
    if (i < n) out[i] = (f16)in[i];
}

// transpose + cast (H_ x H_): out[n*H + k] = in[k*H + n]
__global__ __launch_bounds__(256) void transpose_cast_kernel(const float* __restrict__ in,
                                                             f16* __restrict__ out)
{
    __shared__ float tile[32][33];
    int bx = blockIdx.x * 32, by = blockIdx.y * 32;
    int tx = threadIdx.x & 31, ty = threadIdx.x >> 5;   // ty 0..7
#pragma unroll
    for (int r = 0; r < 32; r += 8)
        tile[ty + r][tx] = in[(size_t)(by + ty + r) * H_ + bx + tx];
    __syncthreads();
#pragma unroll
    for (int r = 0; r < 32; r += 8)
        out[(size_t)(bx + ty + r) * H_ + by + tx] = (f16)tile[tx][ty + r];
}

// ---------------------------------------------------------------------------
// MFMA fp16 GEMM: C(M,N) = A(M,K)f16 @ Bt(N,K)f16^T, C = f32 or f16.
// 128x128 tile, BK=32, 256 threads (4 waves, 2x2 wave grid, 64x64 per wave).
//
// v_mfma_f32_16x16x32_f16 operand layout (2xK extension of classic 16x16x16):
//   A: lane l holds A[row=l&15][k],    k = 4*(l>>4)+j (j=0..3), 16+4*(l>>4)+(j-4) (j=4..7)
//   B: lane l holds B[k][col=l&15],    same k pattern
//   D: D[row=(l>>4)*4+reg][col=l&15]   (m89/m91-verified)
//
// LDS row = 64 bytes = 4 groups of 16B. Group g holds k = {4g..4g+3, 16+4g..16+4g+3}
// so one ds_read_b128 at group (l>>4) yields the lane's full 8-elem fragment.
// Groups are XOR-swizzled by ((row>>1)&3) to spread banks.
// ---------------------------------------------------------------------------
template <typename OutT>
__global__ __launch_bounds__(256) void hgemm_kernel(
    const f16* __restrict__ A, int lda,
    const f16* __restrict__ Bt, int ldb,
    OutT* __restrict__ C, int ldc, int K)
{
    __shared__ f16 As[128 * 32];
    __shared__ f16 Bs[128 * 32];

    const int tid  = threadIdx.x;
    const int lane = tid & 63;
    const int wid  = tid >> 6;
    const int wr   = wid >> 1;
    const int wc   = wid & 1;
    const int m0   = blockIdx.y * 128;
    const int n0   = blockIdx.x * 128;
    const int rsel = lane & 15;
    const int kb   = lane >> 4;

    f32x4 acc[4][4];
#pragma unroll
    for (int m = 0; m < 4; ++m)
#pragma unroll
        for (int n = 0; n < 4; ++n) acc[m][n] = (f32x4)0.f;

    for (int k0 = 0; k0 < K; k0 += 32) {
        // ---- stage 128x32 A and B tiles into LDS (k-half-split groups) ----
#pragma unroll
        for (int r = 0; r < 2; ++r) {
            int li   = r * 256 + tid;
            int row  = li >> 2;          // 0..127
            int s    = li & 3;           // 8-element k-chunk: k = 8s..8s+7
            int key  = (row >> 1) & 3;
            // half h of slot s (k = 8s+4h..8s+4h+3) belongs to group (s&1)*2+h,
            // byte sub-offset (s>>1)*8 within the group.
            int g0   = (((s & 1) * 2 + 0) ^ key);
            int g1   = (((s & 1) * 2 + 1) ^ key);
            int off0 = row * 64 + g0 * 16 + (s >> 1) * 8;
            int off1 = row * 64 + g1 * 16 + (s >> 1) * 8;

            f16x8 av = *(const f16x8*)(A + (size_t)(m0 + row) * lda + k0 + s * 8);
            f16x8 bv = *(const f16x8*)(Bt + (size_t)(n0 + row) * ldb + k0 + s * 8);
            f16x4 alo = {av[0], av[1], av[2], av[3]};
            f16x4 ahi = {av[4], av[5], av[6], av[7]};
            f16x4 blo = {bv[0], bv[1], bv[2], bv[3]};
            f16x4 bhi = {bv[4], bv[5], bv[6], bv[7]};
            *(f16x4*)((char*)As + off0) = alo;
            *(f16x4*)((char*)As + off1) = ahi;
            *(f16x4*)((char*)Bs + off0) = blo;
            *(f16x4*)((char*)Bs + off1) = bhi;
        }
        __syncthreads();

        // ---- fragments + MFMA ----
        f16x8 af[4], bf[4];
#pragma unroll
        for (int m = 0; m < 4; ++m) {
            int row = wr * 64 + m * 16 + rsel;
            af[m] = *(const f16x8*)((char*)As + row * 64 + ((kb ^ ((row >> 1) & 3)) << 4));
        }
#pragma unroll
        for (int n = 0; n < 4; ++n) {
            int row = wc * 64 + n * 16 + rsel;
            bf[n] = *(const f16x8*)((char*)Bs + row * 64 + ((kb ^ ((row >> 1) & 3)) << 4));
        }
#pragma unroll
        for (int m = 0; m < 4; ++m)
#pragma unroll
            for (int n = 0; n < 4; ++n)
                acc[m][n] = __builtin_amdgcn_mfma_f32_16x16x32_f16(af[m], bf[n], acc[m][n], 0, 0, 0);
        __syncthreads();
    }

    // ---- epilogue ----
#pragma unroll
    for (int m = 0; m < 4; ++m) {
        int row0 = m0 + wr * 64 + m * 16 + (lane >> 4) * 4;
#pragma unroll
        for (int n = 0; n < 4; ++n) {
            int col = n0 + wc * 64 + n * 16 + (lane & 15);
#pragma unroll
            for (int r = 0; r < 4; ++r)
                C[(size_t)(row0 + r) * ldc + col] = (OutT)acc[m][n][r];
        }
    }
}

// ---------------------------------------------------------------------------
// Fused elementwise kernels
// ---------------------------------------------------------------------------
__global__ void gru_enc_kernel(const float* __restrict__ gi, const float* __restrict__ gh,
                               const float* __restrict__ bih, const float* __restrict__ bhh,
                               float* __restrict__ h,
                               f16* __restrict__ he_t,          // he16 + t*H
                               f16* __restrict__ hs,            // scaled h for next gh GEMM
                               const float* __restrict__ tg_cur,   // tg + t*B
                               const float* __restrict__ tg_next)  // tg + (t+1)*B
{
    int i = blockIdx.x * blockDim.x + threadIdx.x;   // B*H
    int b = i >> 10;
    int j = i & (H_ - 1);
    size_t base = (size_t)b * H3_;
    float ir = gi[base + j] + bih[j];
    float iz = gi[base + H_ + j] + bih[H_ + j];
    float ig = gi[base + 2 * H_ + j] + bih[2 * H_ + j];
    float hr = gh[base + j] + bhh[j];
    float hz = gh[base + H_ + j] + bhh[H_ + j];
    float hg = gh[base + 2 * H_ + j] + bhh[2 * H_ + j];
    float r = 1.f / (1.f + expf(-(ir + hr)));
    float z = 1.f / (1.f + expf(-(iz + hz)));
    float g = tanhf(ig + r * hg);
    float hprev = tg_cur[b] * h[i];            // reference: gru_cell(x, t*h) -> leak uses t*h
    float hn = (1.f - z) * g + z * hprev;
    h[i] = hn;
    he_t[(size_t)b * N_ * H_ + j] = (f16)hn;
    hs[i] = (f16)(tg_next[b] * hn);
}

__global__ void gru_dec_kernel(const float* __restrict__ gi, const float* __restrict__ gh,
                               const float* __restrict__ bih, const float* __restrict__ bhh,
                               float* __restrict__ h,
                               f16* __restrict__ hc)        // h for W2 GEMM
{
    int i = blockIdx.x * blockDim.x + threadIdx.x;
    int b = i >> 10;
    int j = i & (H_ - 1);
    size_t base = (size_t)b * H3_;
    float ir = gi[base + j] + bih[j];
    float iz = gi[base + H_ + j] + bih[H_ + j];
    float ig = gi[base + 2 * H_ + j] + bih[2 * H_ + j];
    float hr = gh[base + j] + bhh[j];
    float hz = gh[base + H_ + j] + bhh[H_ + j];
    float hg = gh[base + 2 * H_ + j] + bhh[2 * H_ + j];
    float r = 1.f / (1.f + expf(-(ir + hr)));
    float z = 1.f / (1.f + expf(-(iz + hz)));
    float g = tanhf(ig + r * hg);
    float hn = (1.f - z) * g + z * h[i];       // h[i] holds mixed hidden (correct)
    h[i] = hn;
    hc[i] = (f16)hn;
}

__global__ void init_hidden_kernel(float* __restrict__ h,
                                   const f16* __restrict__ he,
                                   const int* __restrict__ idx)
{
    int i = blockIdx.x * blockDim.x + threadIdx.x;
    int b = i >> 10;
    int j = i & (H_ - 1);
    h[i] = (float)he[(size_t)b * N_ * H_ + (size_t)idx[b * N_] * H_ + j];
}

__global__ void init_input_kernel(f16* __restrict__ inp, const float* __restrict__ tok)
{
    int i = blockIdx.x * blockDim.x + threadIdx.x;
    inp[i] = (f16)tok[i & (I_ - 1)];
}

__global__ void mix_hidden_kernel(float* __restrict__ h,
                                  f16* __restrict__ hs,
                                  const f16* __restrict__ he,
                                  const int* __restrict__ idx,   // idx_base + t
                                  const float* __restrict__ tg)  // tg + t*B
{
    int i = blockIdx.x * blockDim.x + threadIdx.x;
    int b = i >> 10;
    int j = i & (H_ - 1);
    float t = tg[b];
    float ih = (float)he[(size_t)b * N_ * H_ + (size_t)idx[b * N_] * H_ + j];
    float hm = t * h[i] + (1.f - t) * ih;
    h[i]  = hm;
    hs[i] = (f16)hm;
}

__global__ void mix_input_kernel(f16* __restrict__ inp,
                                 const float* __restrict__ tok,
                                 const float* __restrict__ tg)
{
    int i = blockIdx.x * blockDim.x + threadIdx.x;   // B*I
    int b = i >> 8;
    float t = tg[b];
    inp[i] = (f16)(t * (float)inp[i] + (1.f - t) * tok[i & (I_ - 1)]);
}

// ---------------------------------------------------------------------------
// Attention step: u = tanh(W1xe + hW2) @ v ; masked softmax ; inp = attn @ input
// ---------------------------------------------------------------------------
__global__ __launch_bounds__(256) void attn_kernel(
    const f16*   __restrict__ w1xe,   // (B,N,H) f16
    const float* __restrict__ hw2,    // (B,H)
    const float* __restrict__ v,      // (H)
    const float* __restrict__ phis,   // (B,N,N)
    const float* __restrict__ input,  // (B,N,I)
    float* __restrict__ out,          // (B,N,N)
    f16*   __restrict__ inp_step,     // (B,I) f16
    int t)
{
    int b   = blockIdx.x;
    int tid = threadIdx.x;
    __shared__ float hw2s[H_];
    __shared__ float vs[H_];
    __shared__ float un[N_];
    __shared__ float attns[N_];
    __shared__ float red[4];

    for (int k = tid; k < H_; k += 256) {
        hw2s[k] = hw2[(size_t)b * H_ + k];
        vs[k]   = v[k];
    }
    __syncthreads();

    for (int n = 0; n < N_; ++n) {
        const f16* wrow = w1xe + ((size_t)(b * N_ + n)) * H_;
        float s = 0.f;
        for (int k = tid; k < H_; k += 256)
            s += tanhf((float)wrow[k] + hw2s[k]) * vs[k];
        for (int off = 32; off; off >>= 1) s += __shfl_down(s, off, 64);
        if ((tid & 63) == 0) red[tid >> 6] = s;
        __syncthreads();
        if (tid == 0) un[n] = red[0] + red[1] + red[2] + red[3];
        __syncthreads();
    }

    if (tid == 0) {
        float mk[N_], um[N_], e[N_];
        float m = -1e30f;
        for (int n = 0; n < N_; ++n) {
            mk[n] = phis[(size_t)b * N_ * N_ + t * N_ + n];
            um[n] = un[n] * mk[n];
            m = fmaxf(m, um[n]);
        }
        float ssum = 0.f;
        for (int n = 0; n < N_; ++n) { e[n] = expf(um[n] - m) * mk[n]; ssum += e[n]; }
        float inv = 1.f / ssum;
        for (int n = 0; n < N_; ++n) {
            float a = e[n] * inv;
            attns[n] = a;
            out[(size_t)b * N_ * N_ + t * N_ + n] = a;
        }
    }
    __syncthreads();

    {
        int i = tid;   // I_ == 256 == blockDim
        float acc = 0.f;
        for (int n = 0; n < N_; ++n)
            acc += attns[n] * input[((size_t)b * N_ + n) * I_ + i];
        inp_step[(size_t)b * I_ + i] = (f16)acc;
    }
}

// ---------------------------------------------------------------------------
// Launcher
// ---------------------------------------------------------------------------
extern "C" void kernel_launch(void* const* d_in, const int* in_sizes, int n_in,
                              void* d_out, int out_size, void* d_ws, size_t ws_size,
                              hipStream_t stream)
{
    const float* input      = (const float*)d_in[0];
    const float* phis       = (const float*)d_in[1];
    const float* init_token = (const float*)d_in[2];
    const float* W1         = (const float*)d_in[3];
    const float* W2         = (const float*)d_in[4];
    const float* v          = (const float*)d_in[5];
    const float* Wih_e      = (const float*)d_in[6];
    const float* Whh_e      = (const float*)d_in[7];
    const float* bih_e      = (const float*)d_in[8];
    const float* bhh_e      = (const float*)d_in[9];
    const float* Wih_d      = (const float*)d_in[10];
    const float* Whh_d      = (const float*)d_in[11];
    const float* bih_d      = (const float*)d_in[12];
    const float* bhh_d      = (const float*)d_in[13];
    float* out = (float*)d_out;

    char* p = (char*)d_ws;
    f16*  he16   = (f16*)p;  p += (size_t)B_ * N_ * H_ * 2;   // 32 MB
    f16*  w1xe16 = (f16*)p;  p += (size_t)B_ * N_ * H_ * 2;   // 32 MB
    float* h     = (float*)p; p += (size_t)B_ * H_ * 4;       //  4 MB
    f16*  hs16   = (f16*)p;  p += (size_t)B_ * H_ * 2;        //  2 MB
    f16*  hc16   = (f16*)p;  p += (size_t)B_ * H_ * 2;        //  2 MB
    f16*  inp16  = (f16*)p;  p += (size_t)B_ * I_ * 2;        // 0.5 MB
    float* gi    = (float*)p; p += (size_t)B_ * H3_ * 4;      // 12 MB
    float* gh    = (float*)p; p += (size_t)B_ * H3_ * 4;      // 12 MB
    float* hw2   = (float*)p; p += (size_t)B_ * H_ * 4;       //  4 MB
    f16*  in16   = (f16*)p;  p += (size_t)B_ * N_ * I_ * 2;   //  8 MB
    f16*  Wih_e16 = (f16*)p; p += (size_t)H3_ * I_ * 2;       // 1.5 MB
    f16*  Whh_e16 = (f16*)p; p += (size_t)H3_ * H_ * 2;       //  6 MB
    f16*  Wih_d16 = (f16*)p; p += (size_t)H3_ * I_ * 2;       // 1.5 MB
    f16*  Whh_d16 = (f16*)p; p += (size_t)H3_ * H_ * 2;       //  6 MB
    f16*  W1t16  = (f16*)p;  p += (size_t)H_ * H_ * 2;        //  2 MB
    f16*  W2t16  = (f16*)p;  p += (size_t)H_ * H_ * 2;        //  2 MB
    float* tg    = (float*)p; p += (size_t)17 * B_ * 4;
    int*   idx   = (int*)p;   p += (size_t)B_ * N_ * 4;

    const int BHBLK = (B_ * H_) / 256;   // 4096
    const int BIBLK = (B_ * I_) / 256;   // 1024

    precompute_kernel<<<4, 256, 0, stream>>>(phis, tg, idx);

    // one-time casts
    cast_kernel<<<(B_ * N_ * I_) / 256, 256, 0, stream>>>(input, in16, B_ * N_ * I_);
    cast_kernel<<<(H3_ * I_) / 256, 256, 0, stream>>>(Wih_e, Wih_e16, H3_ * I_);
    cast_kernel<<<(H3_ * H_) / 256, 256, 0, stream>>>(Whh_e, Whh_e16, H3_ * H_);
    cast_kernel<<<(H3_ * I_) / 256, 256, 0, stream>>>(Wih_d, Wih_d16, H3_ * I_);
    cast_kernel<<<(H3_ * H_) / 256, 256, 0, stream>>>(Whh_d, Whh_d16, H3_ * H_);
    transpose_cast_kernel<<<dim3(32, 32), 256, 0, stream>>>(W1, W1t16);
    transpose_cast_kernel<<<dim3(32, 32), 256, 0, stream>>>(W2, W2t16);

    // ---------------- encoder ----------------
    hipMemsetAsync(h, 0, (size_t)B_ * H_ * 4, stream);
    hipMemsetAsync(hs16, 0, (size_t)B_ * H_ * 2, stream);
    for (int t = 0; t < N_; ++t) {
        hgemm_kernel<float><<<dim3(H3_ / 128, B_ / 128), 256, 0, stream>>>(
            in16 + (size_t)t * I_, N_ * I_, Wih_e16, I_, gi, H3_, I_);
        hgemm_kernel<float><<<dim3(H3_ / 128, B_ / 128), 256, 0, stream>>>(
            hs16, H_, Whh_e16, H_, gh, H3_, H_);
        gru_enc_kernel<<<BHBLK, 256, 0, stream>>>(gi, gh, bih_e, bhh_e,
                                                  h, he16 + (size_t)t * H_, hs16,
                                                  tg + (size_t)t * B_,
                                                  tg + (size_t)(t + 1) * B_);
    }

    // ---------------- W1xe = he @ W1 (f16 out) ----------------
    hgemm_kernel<f16><<<dim3(H_ / 128, (B_ * N_) / 128), 256, 0, stream>>>(
        he16, H_, W1t16, H_, w1xe16, H_, H_);

    // ---------------- decoder ----------------
    init_hidden_kernel<<<BHBLK, 256, 0, stream>>>(h, he16, idx);
    init_input_kernel<<<BIBLK, 256, 0, stream>>>(inp16, init_token);
    for (int t = 0; t < N_; ++t) {
        mix_hidden_kernel<<<BHBLK, 256, 0, stream>>>(h, hs16, he16, idx + t, tg + (size_t)t * B_);
        mix_input_kernel<<<BIBLK, 256, 0, stream>>>(inp16, init_token, tg + (size_t)t * B_);
        hgemm_kernel<float><<<dim3(H3_ / 128, B_ / 128), 256, 0, stream>>>(
            inp16, I_, Wih_d16, I_, gi, H3_, I_);
        hgemm_kernel<float><<<dim3(H3_ / 128, B_ / 128), 256, 0, stream>>>(
            hs16, H_, Whh_d16, H_, gh, H3_, H_);
        gru_dec_kernel<<<BHBLK, 256, 0, stream>>>(gi, gh, bih_d, bhh_d, h, hc16);
        hgemm_kernel<float><<<dim3(H_ / 128, B_ / 128), 256, 0, stream>>>(
            hc16, H_, W2t16, H_, hw2, H_, H_);
        attn_kernel<<<B_, 256, 0, stream>>>(w1xe16, hw2, v, phis, input, out, inp16, t);
    }
}

// Round 4
// 2009.313 us; speedup vs baseline: 3.0905x; 1.2633x over previous
//
#include <hip/hip_runtime.h>
#include <math.h>

#define B_  1024
#define N_  16
#define I_  256
#define H_  1024
#define H3_ 3072

typedef _Float16 f16;
typedef _Float16 f16x4 __attribute__((ext_vector_type(4)));
typedef _Float16 f16x8 __attribute__((ext_vector_type(8)));
typedef float    f32x4 __attribute__((ext_vector_type(4)));

__device__ __forceinline__ float sigmoidf_(float x) { return 1.f / (1.f + expf(-x)); }

// ---------------------------------------------------------------------------
// Precompute t_gate (17,B) and idx_seq (B,N)
// ---------------------------------------------------------------------------
__global__ void precompute_kernel(const float* __restrict__ phis,
                                  float* __restrict__ tg,
                                  int* __restrict__ idx)
{
    int b = blockIdx.x * blockDim.x + threadIdx.x;
    if (b >= B_) return;
    tg[b] = 1.0f;
    for (int t = 1; t < N_; ++t)
        tg[t * B_ + b] = phis[(size_t)b * N_ * N_ + t * N_ + (t - 1)];
    tg[16 * B_ + b] = 0.0f;   // sentinel for encoder t=15's hs write (unused)
    for (int t = 0; t < N_; ++t) {
        float ns = 0.f;
        for (int k = 0; k < N_; ++k) ns += phis[(size_t)b * N_ * N_ + t * N_ + k];
        int nsi = (int)(ns + 0.5f);
        idx[b * N_ + t] = (nsi + t - 1) % N_;
    }
}

// ---------------------------------------------------------------------------
// Casts
// ---------------------------------------------------------------------------
__global__ void cast_kernel(const float* __restrict__ in, f16* __restrict__ out, int n)
{
    int i = blockIdx.x * blockDim.x + threadIdx.x;
    if (i < n) out[i] = (f16)in[i];
}

__global__ __launch_bounds__(256) void transpose_cast_kernel(const float* __restrict__ in,
                                                             f16* __restrict__ out)
{
    __shared__ float tile[32][33];
    int bx = blockIdx.x * 32, by = blockIdx.y * 32;
    int tx = threadIdx.x & 31, ty = threadIdx.x >> 5;
#pragma unroll
    for (int r = 0; r < 32; r += 8)
        tile[ty + r][tx] = in[(size_t)(by + ty + r) * H_ + bx + tx];
    __syncthreads();
#pragma unroll
    for (int r = 0; r < 32; r += 8)
        out[(size_t)(bx + ty + r) * H_ + by + tx] = (f16)tile[tx][ty + r];
}

// ---------------------------------------------------------------------------
// LDS layout helpers (k-half-split groups, verified in round 3):
// row = 64 bytes = 4 groups of 16B. Group g holds k = {4g..4g+3, 16+4g..16+4g+3}
// with XOR swizzle by ((row>>1)&3). One ds_read_b128 at group (lane>>4)^key
// yields the lane's full 8-elem mfma_16x16x32 fragment.
// ---------------------------------------------------------------------------
#define STAGE_ROW(dst, rowexpr, srcptr)                                        \
    {                                                                          \
        int row = rowexpr, s = tid & 3;                                        \
        int key = (row >> 1) & 3;                                              \
        int g0  = (((s & 1) * 2 + 0) ^ key);                                   \
        int g1  = (((s & 1) * 2 + 1) ^ key);                                   \
        f16x8 vv = *(const f16x8*)(srcptr);                                    \
        f16x4 lo = {vv[0], vv[1], vv[2], vv[3]};                               \
        f16x4 hi = {vv[4], vv[5], vv[6], vv[7]};                               \
        *(f16x4*)((char*)(dst) + row * 64 + g0 * 16 + (s >> 1) * 8) = lo;      \
        *(f16x4*)((char*)(dst) + row * 64 + g1 * 16 + (s >> 1) * 8) = hi;      \
    }

// ---------------------------------------------------------------------------
// 128x128 MFMA GEMM (W1xe only): C(M,N) = A @ Bt^T, f16 out.
// XCD-chunked swizzle: each XCD owns contiguous m-panels -> A stays in its L2.
// ---------------------------------------------------------------------------
template <typename OutT>
__global__ __launch_bounds__(256) void hgemm_kernel(
    const f16* __restrict__ A, int lda,
    const f16* __restrict__ Bt, int ldb,
    OutT* __restrict__ C, int ldc, int K)
{
    __shared__ f16 As[128 * 32];
    __shared__ f16 Bs[128 * 32];

    const int tid  = threadIdx.x;
    const int lane = tid & 63;
    const int wid  = tid >> 6;
    const int wr   = wid >> 1;
    const int wc   = wid & 1;
    const int rsel = lane & 15;
    const int kb   = lane >> 4;

    int flat = blockIdx.y * gridDim.x + blockIdx.x;
    int nwg  = gridDim.x * gridDim.y;
    int cpx  = nwg >> 3;
    int nf   = (flat & 7) * cpx + (flat >> 3);
    const int n0 = (int)(nf % gridDim.x) * 128;
    const int m0 = (int)(nf / gridDim.x) * 128;

    f32x4 acc[4][4];
#pragma unroll
    for (int m = 0; m < 4; ++m)
#pragma unroll
        for (int n = 0; n < 4; ++n) acc[m][n] = (f32x4)0.f;

    for (int k0 = 0; k0 < K; k0 += 32) {
#pragma unroll
        for (int r = 0; r < 2; ++r) {
            int li = r * 256 + tid;
            STAGE_ROW(As, li >> 2, A + (size_t)(m0 + (li >> 2)) * lda + k0 + (tid & 3) * 8);
            STAGE_ROW(Bs, li >> 2, Bt + (size_t)(n0 + (li >> 2)) * ldb + k0 + (tid & 3) * 8);
        }
        __syncthreads();

        f16x8 af[4], bf[4];
#pragma unroll
        for (int m = 0; m < 4; ++m) {
            int row = wr * 64 + m * 16 + rsel;
            af[m] = *(const f16x8*)((char*)As + row * 64 + ((kb ^ ((row >> 1) & 3)) << 4));
        }
#pragma unroll
        for (int n = 0; n < 4; ++n) {
            int row = wc * 64 + n * 16 + rsel;
            bf[n] = *(const f16x8*)((char*)Bs + row * 64 + ((kb ^ ((row >> 1) & 3)) << 4));
        }
#pragma unroll
        for (int m = 0; m < 4; ++m)
#pragma unroll
            for (int n = 0; n < 4; ++n)
                acc[m][n] = __builtin_amdgcn_mfma_f32_16x16x32_f16(af[m], bf[n], acc[m][n], 0, 0, 0);
        __syncthreads();
    }

#pragma unroll
    for (int m = 0; m < 4; ++m) {
        int row0 = m0 + wr * 64 + m * 16 + kb * 4;
#pragma unroll
        for (int n = 0; n < 4; ++n) {
            int col = n0 + wc * 64 + n * 16 + rsel;
#pragma unroll
            for (int r = 0; r < 4; ++r)
                C[(size_t)(row0 + r) * ldc + col] = (OutT)acc[m][n][r];
        }
    }
}

// ---------------------------------------------------------------------------
// Fused GEMM + GRU cell. Computes, for a 32(b) x 64(j) tile:
//   gi = A1 @ Bt1^T   (K1=256, 3 gate column-blocks at stride H)
//   gh = A2 @ Bt2^T   (K2=H)
//   r = sig(ir+hr+b), z = sig(iz+hz+b), g = tanh(ig+bg_i + r*(hg+bg_h))
//   hn = (1-z)*g + z*leak;  leak = MODE==0 ? tg_cur*h : h (pre-mixed)
// MODE 0 (encoder): writes h(f32), he16 slice (out_a, stride N*H), hs16=tg_next*hn
// MODE 1 (decoder): writes h(f32), hc16 (out_a, stride H)
// Grid (16 j-tiles, 32 b-tiles), 256 threads = 4 waves (2 row-halves x 2 col-halves).
// ---------------------------------------------------------------------------
template <int MODE>
__global__ __launch_bounds__(256) void gru_fused_kernel(
    const f16* __restrict__ A1, int lda1,
    const f16* __restrict__ Bt1, int ldb1, int K1,
    const f16* __restrict__ A2,
    const f16* __restrict__ Bt2,
    const float* __restrict__ bih, const float* __restrict__ bhh,
    float* __restrict__ h,
    const float* __restrict__ tg_cur,
    const float* __restrict__ tg_next,
    f16* __restrict__ out_a,
    f16* __restrict__ hs)
{
    __shared__ f16 As[32 * 32];
    __shared__ f16 Bs[3 * 64 * 32];

    const int tid  = threadIdx.x;
    const int lane = tid & 63;
    const int wid  = tid >> 6;
    const int wr   = wid >> 1;     // row half: 16 rows each
    const int wc   = wid & 1;      // col half: 32 j each
    const int rsel = lane & 15;
    const int kb   = lane >> 4;

    // XCD-chunked swizzle, j-grouped (per-XCD: 2 j-tiles x all b -> B-rows+A2 fit L2)
    int flat = blockIdx.y * gridDim.x + blockIdx.x;   // grid (16, 32)
    int nf   = (flat & 7) * 64 + (flat >> 3);
    const int j0 = (nf >> 5) * 64;
    const int b0 = (nf & 31) * 32;

    f32x4 acc1[3][2], acc2[3][2];
#pragma unroll
    for (int g = 0; g < 3; ++g)
#pragma unroll
        for (int nt = 0; nt < 2; ++nt) { acc1[g][nt] = (f32x4)0.f; acc2[g][nt] = (f32x4)0.f; }

#pragma unroll
    for (int phase = 0; phase < 2; ++phase) {
        const f16* Ap   = phase ? A2 : A1;
        const f16* Btp  = phase ? Bt2 : Bt1;
        const int  ldap = phase ? H_ : lda1;
        const int  ldbp = phase ? H_ : ldb1;
        const int  Kp   = phase ? H_ : K1;

        for (int k0 = 0; k0 < Kp; k0 += 32) {
            if (tid < 128)
                STAGE_ROW(As, tid >> 2, Ap + (size_t)(b0 + (tid >> 2)) * ldap + k0 + (tid & 3) * 8);
#pragma unroll
            for (int gg = 0; gg < 3; ++gg)
                STAGE_ROW((f16*)Bs + gg * 64 * 32, tid >> 2,
                          Btp + (size_t)(gg * H_ + j0 + (tid >> 2)) * ldbp + k0 + (tid & 3) * 8);
            __syncthreads();

            int arow = wr * 16 + rsel;
            f16x8 af = *(const f16x8*)((char*)As + arow * 64 + ((kb ^ ((arow >> 1) & 3)) << 4));
            f16x8 bf[3][2];
#pragma unroll
            for (int gg = 0; gg < 3; ++gg)
#pragma unroll
                for (int nt = 0; nt < 2; ++nt) {
                    int brow = wc * 32 + nt * 16 + rsel;
                    bf[gg][nt] = *(const f16x8*)((char*)Bs + (gg * 64 + brow) * 64 +
                                                 ((kb ^ ((brow >> 1) & 3)) << 4));
                }
            if (phase == 0) {
#pragma unroll
                for (int gg = 0; gg < 3; ++gg)
#pragma unroll
                    for (int nt = 0; nt < 2; ++nt)
                        acc1[gg][nt] = __builtin_amdgcn_mfma_f32_16x16x32_f16(af, bf[gg][nt], acc1[gg][nt], 0, 0, 0);
            } else {
#pragma unroll
                for (int gg = 0; gg < 3; ++gg)
#pragma unroll
                    for (int nt = 0; nt < 2; ++nt)
                        acc2[gg][nt] = __builtin_amdgcn_mfma_f32_16x16x32_f16(af, bf[gg][nt], acc2[gg][nt], 0, 0, 0);
            }
            __syncthreads();
        }
    }

    // ---- GRU epilogue ----
#pragma unroll
    for (int nt = 0; nt < 2; ++nt) {
        int j = j0 + wc * 32 + nt * 16 + rsel;
        float br_i = bih[j],          br_h = bhh[j];
        float bz_i = bih[H_ + j],     bz_h = bhh[H_ + j];
        float bg_i = bih[2 * H_ + j], bg_h = bhh[2 * H_ + j];
#pragma unroll
        for (int q = 0; q < 4; ++q) {
            int row = b0 + wr * 16 + kb * 4 + q;
            float r = sigmoidf_(acc1[0][nt][q] + br_i + acc2[0][nt][q] + br_h);
            float z = sigmoidf_(acc1[1][nt][q] + bz_i + acc2[1][nt][q] + bz_h);
            float g = tanhf(acc1[2][nt][q] + bg_i + r * (acc2[2][nt][q] + bg_h));
            float leak;
            if (MODE == 0) leak = tg_cur[row] * h[(size_t)row * H_ + j];
            else           leak = h[(size_t)row * H_ + j];
            float hn = (1.f - z) * g + z * leak;
            h[(size_t)row * H_ + j] = hn;
            if (MODE == 0) {
                out_a[(size_t)row * (N_ * H_) + j] = (f16)hn;
                hs[(size_t)row * H_ + j] = (f16)(tg_next[row] * hn);
            } else {
                out_a[(size_t)row * H_ + j] = (f16)hn;
            }
        }
    }
}

// ---------------------------------------------------------------------------
// 64x64 MFMA GEMM for hw2 = h @ W2 (M=N=K=1024), f32 out. 256 blocks.
// ---------------------------------------------------------------------------
__global__ __launch_bounds__(256) void hgemm64_kernel(
    const f16* __restrict__ A, const f16* __restrict__ Bt, float* __restrict__ C)
{
    __shared__ f16 As[64 * 32];
    __shared__ f16 Bs[64 * 32];

    const int tid  = threadIdx.x;
    const int lane = tid & 63;
    const int wid  = tid >> 6;
    const int wr   = wid >> 1;
    const int wc   = wid & 1;
    const int rsel = lane & 15;
    const int kb   = lane >> 4;

    int flat = blockIdx.y * gridDim.x + blockIdx.x;   // grid (16,16)
    int nf   = (flat & 7) * 32 + (flat >> 3);
    const int m0 = (nf >> 4) * 64;
    const int n0 = (nf & 15) * 64;

    f32x4 acc[2][2];
#pragma unroll
    for (int m = 0; m < 2; ++m)
#pragma unroll
        for (int n = 0; n < 2; ++n) acc[m][n] = (f32x4)0.f;

    for (int k0 = 0; k0 < H_; k0 += 32) {
        STAGE_ROW(As, tid >> 2, A + (size_t)(m0 + (tid >> 2)) * H_ + k0 + (tid & 3) * 8);
        STAGE_ROW(Bs, tid >> 2, Bt + (size_t)(n0 + (tid >> 2)) * H_ + k0 + (tid & 3) * 8);
        __syncthreads();

        f16x8 af[2], bf[2];
#pragma unroll
        for (int m = 0; m < 2; ++m) {
            int row = wr * 32 + m * 16 + rsel;
            af[m] = *(const f16x8*)((char*)As + row * 64 + ((kb ^ ((row >> 1) & 3)) << 4));
        }
#pragma unroll
        for (int nt = 0; nt < 2; ++nt) {
            int row = wc * 32 + nt * 16 + rsel;
            bf[nt] = *(const f16x8*)((char*)Bs + row * 64 + ((kb ^ ((row >> 1) & 3)) << 4));
        }
#pragma unroll
        for (int m = 0; m < 2; ++m)
#pragma unroll
            for (int nt = 0; nt < 2; ++nt)
                acc[m][nt] = __builtin_amdgcn_mfma_f32_16x16x32_f16(af[m], bf[nt], acc[m][nt], 0, 0, 0);
        __syncthreads();
    }

#pragma unroll
    for (int m = 0; m < 2; ++m)
#pragma unroll
        for (int nt = 0; nt < 2; ++nt) {
            int col = n0 + wc * 32 + nt * 16 + rsel;
#pragma unroll
            for (int q = 0; q < 4; ++q) {
                int row = m0 + wr * 32 + m * 16 + kb * 4 + q;
                C[(size_t)row * H_ + col] = acc[m][nt][q];
            }
        }
}

// ---------------------------------------------------------------------------
// Decoder init: h = he[b, idx0]; hs = f16(h); inp = init_token
// ---------------------------------------------------------------------------
__global__ void dec_init_kernel(float* __restrict__ h, f16* __restrict__ hs,
                                const f16* __restrict__ he, const int* __restrict__ idx)
{
    int i = blockIdx.x * blockDim.x + threadIdx.x;   // B*H
    int b = i >> 10;
    int j = i & (H_ - 1);
    float v0 = (float)he[(size_t)b * N_ * H_ + (size_t)idx[b * N_] * H_ + j];
    h[i]  = v0;
    hs[i] = (f16)v0;
}

__global__ void init_input_kernel(f16* __restrict__ inp, const float* __restrict__ tok)
{
    int i = blockIdx.x * blockDim.x + threadIdx.x;   // B*I
    inp[i] = (f16)tok[i & (I_ - 1)];
}

// ---------------------------------------------------------------------------
// Attention + (optionally) next-step mix:
//   u = tanh(w1xe + hw2) @ v ; masked softmax -> out[:, t, :]
//   inp_attn = attn @ input
//   MIX: inp_next = tn*inp_attn + (1-tn)*tok ; h = tn*h + (1-tn)*he[idx_next]
// ---------------------------------------------------------------------------
template <int MIX>
__global__ __launch_bounds__(256) void attn_kernel(
    const f16*   __restrict__ w1xe,
    const float* __restrict__ hw2,
    const float* __restrict__ v,
    const float* __restrict__ phis,
    const float* __restrict__ input,
    float* __restrict__ out,
    f16*   __restrict__ inp_step,
    int t,
    const float* __restrict__ tg_next,    // tg + (t+1)*B
    const int*   __restrict__ idx_next,   // idx + (t+1)
    const f16*   __restrict__ he,
    float* __restrict__ h,
    f16*   __restrict__ hs,
    const float* __restrict__ tok)
{
    int b   = blockIdx.x;
    int tid = threadIdx.x;
    __shared__ float hw2s[H_];
    __shared__ float vs[H_];
    __shared__ float un[N_];
    __shared__ float attns[N_];
    __shared__ float red[4];

    for (int k = tid; k < H_; k += 256) {
        hw2s[k] = hw2[(size_t)b * H_ + k];
        vs[k]   = v[k];
    }
    __syncthreads();

    for (int n = 0; n < N_; ++n) {
        const f16* wrow = w1xe + ((size_t)(b * N_ + n)) * H_;
        float s = 0.f;
        for (int k = tid; k < H_; k += 256)
            s += tanhf((float)wrow[k] + hw2s[k]) * vs[k];
        for (int off = 32; off; off >>= 1) s += __shfl_down(s, off, 64);
        if ((tid & 63) == 0) red[tid >> 6] = s;
        __syncthreads();
        if (tid == 0) un[n] = red[0] + red[1] + red[2] + red[3];
        __syncthreads();
    }

    if (tid == 0) {
        float mk[N_], um[N_], e[N_];
        float m = -1e30f;
        for (int n = 0; n < N_; ++n) {
            mk[n] = phis[(size_t)b * N_ * N_ + t * N_ + n];
            um[n] = un[n] * mk[n];
            m = fmaxf(m, um[n]);
        }
        float ssum = 0.f;
        for (int n = 0; n < N_; ++n) { e[n] = expf(um[n] - m) * mk[n]; ssum += e[n]; }
        float inv = 1.f / ssum;
        for (int n = 0; n < N_; ++n) {
            float a = e[n] * inv;
            attns[n] = a;
            out[(size_t)b * N_ * N_ + t * N_ + n] = a;
        }
    }
    __syncthreads();

    float acc = 0.f;
    for (int n = 0; n < N_; ++n)
        acc += attns[n] * input[((size_t)b * N_ + n) * I_ + tid];

    if (MIX) {
        float tn = tg_next[b];
        inp_step[(size_t)b * I_ + tid] = (f16)(tn * acc + (1.f - tn) * tok[tid]);
        int id = idx_next[b * N_];
        for (int j = tid; j < H_; j += 256) {
            float ih = (float)he[(size_t)b * N_ * H_ + (size_t)id * H_ + j];
            float hm = tn * h[(size_t)b * H_ + j] + (1.f - tn) * ih;
            h[(size_t)b * H_ + j]  = hm;
            hs[(size_t)b * H_ + j] = (f16)hm;
        }
    } else {
        inp_step[(size_t)b * I_ + tid] = (f16)acc;
    }
}

// ---------------------------------------------------------------------------
// Launcher
// ---------------------------------------------------------------------------
extern "C" void kernel_launch(void* const* d_in, const int* in_sizes, int n_in,
                              void* d_out, int out_size, void* d_ws, size_t ws_size,
                              hipStream_t stream)
{
    const float* input      = (const float*)d_in[0];
    const float* phis       = (const float*)d_in[1];
    const float* init_token = (const float*)d_in[2];
    const float* W1         = (const float*)d_in[3];
    const float* W2         = (const float*)d_in[4];
    const float* v          = (const float*)d_in[5];
    const float* Wih_e      = (const float*)d_in[6];
    const float* Whh_e      = (const float*)d_in[7];
    const float* bih_e      = (const float*)d_in[8];
    const float* bhh_e      = (const float*)d_in[9];
    const float* Wih_d      = (const float*)d_in[10];
    const float* Whh_d      = (const float*)d_in[11];
    const float* bih_d      = (const float*)d_in[12];
    const float* bhh_d      = (const float*)d_in[13];
    float* out = (float*)d_out;

    char* p = (char*)d_ws;
    f16*  he16    = (f16*)p;  p += (size_t)B_ * N_ * H_ * 2;   // 32 MB
    f16*  w1xe16  = (f16*)p;  p += (size_t)B_ * N_ * H_ * 2;   // 32 MB
    float* h      = (float*)p; p += (size_t)B_ * H_ * 4;       //  4 MB
    f16*  hs16    = (f16*)p;  p += (size_t)B_ * H_ * 2;        //  2 MB
    f16*  hc16    = (f16*)p;  p += (size_t)B_ * H_ * 2;        //  2 MB
    f16*  inp16   = (f16*)p;  p += (size_t)B_ * I_ * 2;        // 0.5 MB
    float* hw2    = (float*)p; p += (size_t)B_ * H_ * 4;       //  4 MB
    f16*  in16    = (f16*)p;  p += (size_t)B_ * N_ * I_ * 2;   //  8 MB
    f16*  Wih_e16 = (f16*)p;  p += (size_t)H3_ * I_ * 2;
    f16*  Whh_e16 = (f16*)p;  p += (size_t)H3_ * H_ * 2;
    f16*  Wih_d16 = (f16*)p;  p += (size_t)H3_ * I_ * 2;
    f16*  Whh_d16 = (f16*)p;  p += (size_t)H3_ * H_ * 2;
    f16*  W1t16   = (f16*)p;  p += (size_t)H_ * H_ * 2;
    f16*  W2t16   = (f16*)p;  p += (size_t)H_ * H_ * 2;
    float* tg     = (float*)p; p += (size_t)17 * B_ * 4;
    int*   idx    = (int*)p;   p += (size_t)B_ * N_ * 4;

    const int BHBLK = (B_ * H_) / 256;
    const int BIBLK = (B_ * I_) / 256;
    const dim3 gru_grid(16, 32);    // j-tiles x b-tiles

    precompute_kernel<<<4, 256, 0, stream>>>(phis, tg, idx);

    cast_kernel<<<(B_ * N_ * I_) / 256, 256, 0, stream>>>(input, in16, B_ * N_ * I_);
    cast_kernel<<<(H3_ * I_) / 256, 256, 0, stream>>>(Wih_e, Wih_e16, H3_ * I_);
    cast_kernel<<<(H3_ * H_) / 256, 256, 0, stream>>>(Whh_e, Whh_e16, H3_ * H_);
    cast_kernel<<<(H3_ * I_) / 256, 256, 0, stream>>>(Wih_d, Wih_d16, H3_ * I_);
    cast_kernel<<<(H3_ * H_) / 256, 256, 0, stream>>>(Whh_d, Whh_d16, H3_ * H_);
    transpose_cast_kernel<<<dim3(32, 32), 256, 0, stream>>>(W1, W1t16);
    transpose_cast_kernel<<<dim3(32, 32), 256, 0, stream>>>(W2, W2t16);

    // ---------------- encoder: one fused kernel per step ----------------
    hipMemsetAsync(h, 0, (size_t)B_ * H_ * 4, stream);
    hipMemsetAsync(hs16, 0, (size_t)B_ * H_ * 2, stream);
    for (int t = 0; t < N_; ++t) {
        gru_fused_kernel<0><<<gru_grid, 256, 0, stream>>>(
            in16 + (size_t)t * I_, N_ * I_, Wih_e16, I_, I_,
            hs16, Whh_e16, bih_e, bhh_e, h,
            tg + (size_t)t * B_, tg + (size_t)(t + 1) * B_,
            he16 + (size_t)t * H_, hs16);
    }

    // ---------------- W1xe = he @ W1 (f16 out) ----------------
    hgemm_kernel<f16><<<dim3(H_ / 128, (B_ * N_) / 128), 256, 0, stream>>>(
        he16, H_, W1t16, H_, w1xe16, H_, H_);

    // ---------------- decoder ----------------
    dec_init_kernel<<<BHBLK, 256, 0, stream>>>(h, hs16, he16, idx);
    init_input_kernel<<<BIBLK, 256, 0, stream>>>(inp16, init_token);
    for (int t = 0; t < N_; ++t) {
        gru_fused_kernel<1><<<gru_grid, 256, 0, stream>>>(
            inp16, I_, Wih_d16, I_, I_,
            hs16, Whh_d16, bih_d, bhh_d, h,
            nullptr, nullptr, hc16, nullptr);
        hgemm64_kernel<<<dim3(16, 16), 256, 0, stream>>>(hc16, W2t16, hw2);
        if (t < N_ - 1)
            attn_kernel<1><<<B_, 256, 0, stream>>>(
                w1xe16, hw2, v, phis, input, out, inp16, t,
                tg + (size_t)(t + 1) * B_, idx + (t + 1), he16, h, hs16, init_token);
        else
            attn_kernel<0><<<B_, 256, 0, stream>>>(
                w1xe16, hw2, v, phis, input, out, inp16, t,
                tg, idx, he16, h, hs16, init_token);
    }
}

// Round 5
// 1826.578 us; speedup vs baseline: 3.3997x; 1.1000x over previous
//
#include <hip/hip_runtime.h>
#include <math.h>

#define B_  1024
#define N_  16
#define I_  256
#define H_  1024
#define H3_ 3072

typedef _Float16 f16;
typedef _Float16 f16x4 __attribute__((ext_vector_type(4)));
typedef _Float16 f16x8 __attribute__((ext_vector_type(8)));
typedef float    f32x4 __attribute__((ext_vector_type(4)));

__device__ __forceinline__ float sigmoidf_(float x) { return 1.f / (1.f + expf(-x)); }

// ---------------------------------------------------------------------------
// Precompute t_gate (17,B) and idx_seq (B,N)
// ---------------------------------------------------------------------------
__global__ void precompute_kernel(const float* __restrict__ phis,
                                  float* __restrict__ tg,
                                  int* __restrict__ idx)
{
    int b = blockIdx.x * blockDim.x + threadIdx.x;
    if (b >= B_) return;
    tg[b] = 1.0f;
    for (int t = 1; t < N_; ++t)
        tg[t * B_ + b] = phis[(size_t)b * N_ * N_ + t * N_ + (t - 1)];
    tg[16 * B_ + b] = 0.0f;
    for (int t = 0; t < N_; ++t) {
        float ns = 0.f;
        for (int k = 0; k < N_; ++k) ns += phis[(size_t)b * N_ * N_ + t * N_ + k];
        int nsi = (int)(ns + 0.5f);
        idx[b * N_ + t] = (nsi + t - 1) % N_;
    }
}

// ---------------------------------------------------------------------------
// Casts
// ---------------------------------------------------------------------------
__global__ void cast_kernel(const float* __restrict__ in, f16* __restrict__ out, int n)
{
    int i = blockIdx.x * blockDim.x + threadIdx.x;
    if (i < n) out[i] = (f16)in[i];
}

__global__ void cast4_kernel(const float* __restrict__ s0, f16* __restrict__ d0, int n0,
                             const float* __restrict__ s1, f16* __restrict__ d1, int n1,
                             const float* __restrict__ s2, f16* __restrict__ d2, int n2,
                             const float* __restrict__ s3, f16* __restrict__ d3, int n3)
{
    int i = blockIdx.x * blockDim.x + threadIdx.x;
    int T0 = n0, T1 = T0 + n1, T2 = T1 + n2, T3 = T2 + n3;
    if (i < T0) d0[i] = (f16)s0[i];
    else if (i < T1) d1[i - T0] = (f16)s1[i - T0];
    else if (i < T2) d2[i - T1] = (f16)s2[i - T1];
    else if (i < T3) d3[i - T2] = (f16)s3[i - T2];
}

// transpose+cast two HxH matrices (z selects)
__global__ __launch_bounds__(256) void transpose_cast2_kernel(
    const float* __restrict__ in0, f16* __restrict__ out0,
    const float* __restrict__ in1, f16* __restrict__ out1)
{
    const float* in  = blockIdx.z ? in1 : in0;
    f16*        outp = blockIdx.z ? out1 : out0;
    __shared__ float tile[32][33];
    int bx = blockIdx.x * 32, by = blockIdx.y * 32;
    int tx = threadIdx.x & 31, ty = threadIdx.x >> 5;
#pragma unroll
    for (int r = 0; r < 32; r += 8)
        tile[ty + r][tx] = in[(size_t)(by + ty + r) * H_ + bx + tx];
    __syncthreads();
#pragma unroll
    for (int r = 0; r < 32; r += 8)
        outp[(size_t)(bx + ty + r) * H_ + by + tx] = (f16)tile[tx][ty + r];
}

// ---------------------------------------------------------------------------
// LDS layout (verified r3): row = 64B = 4 groups of 16B; group g holds
// k = {4g..4g+3, 16+4g..16+4g+3}; XOR swizzle by ((row>>1)&3).
// One ds_read_b128 at group (lane>>4)^key = full 8-elem mfma_16x16x32 frag.
// ---------------------------------------------------------------------------
#define STAGE_ROW_T(dst, rowexpr, srcptr, t)                                   \
    {                                                                          \
        int row_ = rowexpr, s_ = (t) & 3;                                      \
        int key_ = (row_ >> 1) & 3;                                            \
        int g0_  = (((s_ & 1) * 2 + 0) ^ key_);                                \
        int g1_  = (((s_ & 1) * 2 + 1) ^ key_);                                \
        f16x8 vv_ = *(const f16x8*)(srcptr);                                   \
        f16x4 lo_ = {vv_[0], vv_[1], vv_[2], vv_[3]};                          \
        f16x4 hi_ = {vv_[4], vv_[5], vv_[6], vv_[7]};                          \
        *(f16x4*)((char*)(dst) + row_ * 64 + g0_ * 16 + (s_ >> 1) * 8) = lo_;  \
        *(f16x4*)((char*)(dst) + row_ * 64 + g1_ * 16 + (s_ >> 1) * 8) = hi_;  \
    }

// ---------------------------------------------------------------------------
// 128x128 MFMA GEMM (W1xe): C = A @ Bt^T, f16 out, XCD-chunked swizzle.
// ---------------------------------------------------------------------------
template <typename OutT>
__global__ __launch_bounds__(256) void hgemm_kernel(
    const f16* __restrict__ A, int lda,
    const f16* __restrict__ Bt, int ldb,
    OutT* __restrict__ C, int ldc, int K)
{
    __shared__ f16 As[128 * 32];
    __shared__ f16 Bs[128 * 32];

    const int tid  = threadIdx.x;
    const int lane = tid & 63;
    const int wid  = tid >> 6;
    const int wr   = wid >> 1;
    const int wc   = wid & 1;
    const int rsel = lane & 15;
    const int kb   = lane >> 4;

    int flat = blockIdx.y * gridDim.x + blockIdx.x;
    int nwg  = gridDim.x * gridDim.y;
    int cpx  = nwg >> 3;
    int nf   = (flat & 7) * cpx + (flat >> 3);
    const int n0 = (int)(nf % gridDim.x) * 128;
    const int m0 = (int)(nf / gridDim.x) * 128;

    f32x4 acc[4][4];
#pragma unroll
    for (int m = 0; m < 4; ++m)
#pragma unroll
        for (int n = 0; n < 4; ++n) acc[m][n] = (f32x4)0.f;

    for (int k0 = 0; k0 < K; k0 += 32) {
#pragma unroll
        for (int r = 0; r < 2; ++r) {
            int li = r * 256 + tid;
            STAGE_ROW_T(As, li >> 2, A + (size_t)(m0 + (li >> 2)) * lda + k0 + (tid & 3) * 8, tid);
            STAGE_ROW_T(Bs, li >> 2, Bt + (size_t)(n0 + (li >> 2)) * ldb + k0 + (tid & 3) * 8, tid);
        }
        __syncthreads();

        f16x8 af[4], bf[4];
#pragma unroll
        for (int m = 0; m < 4; ++m) {
            int row = wr * 64 + m * 16 + rsel;
            af[m] = *(const f16x8*)((char*)As + row * 64 + ((kb ^ ((row >> 1) & 3)) << 4));
        }
#pragma unroll
        for (int n = 0; n < 4; ++n) {
            int row = wc * 64 + n * 16 + rsel;
            bf[n] = *(const f16x8*)((char*)Bs + row * 64 + ((kb ^ ((row >> 1) & 3)) << 4));
        }
#pragma unroll
        for (int m = 0; m < 4; ++m)
#pragma unroll
            for (int n = 0; n < 4; ++n)
                acc[m][n] = __builtin_amdgcn_mfma_f32_16x16x32_f16(af[m], bf[n], acc[m][n], 0, 0, 0);
        __syncthreads();
    }

#pragma unroll
    for (int m = 0; m < 4; ++m) {
        int row0 = m0 + wr * 64 + m * 16 + kb * 4;
#pragma unroll
        for (int n = 0; n < 4; ++n) {
            int col = n0 + wc * 64 + n * 16 + rsel;
#pragma unroll
            for (int r = 0; r < 4; ++r)
                C[(size_t)(row0 + r) * ldc + col] = (OutT)acc[m][n][r];
        }
    }
}

// ---------------------------------------------------------------------------
// Fused GEMM + GRU, split-K in block. 512 threads = 2 wave-groups of 4 waves.
// Group wg computes k in [wg*K/2, (wg+1)*K/2) of BOTH GEMM phases into private
// accs + private LDS stage buffers; partials merged via LDS at the end.
// Tile: 32(b) x 64(j) x 3 gates. Grid (16 j-tiles, 32 b-tiles), XCD j-grouped.
// ---------------------------------------------------------------------------
template <int MODE>
__global__ __launch_bounds__(512) void gru_fused_kernel(
    const f16* __restrict__ A1, int lda1,
    const f16* __restrict__ Bt1, int ldb1, int K1,
    const f16* __restrict__ A2,
    const f16* __restrict__ Bt2,
    const float* __restrict__ bih, const float* __restrict__ bhh,
    float* __restrict__ h,
    const float* __restrict__ tg_cur,
    const float* __restrict__ tg_next,
    f16* __restrict__ out_a,
    f16* __restrict__ hs)
{
    __shared__ char smem[28672];   // stage: As[2]@0/2048, Bs[2]@4096/16384; reduce: 24KB @0

    const int tid  = threadIdx.x;
    const int wg   = tid >> 8;       // wave-group 0/1
    const int ltid = tid & 255;
    const int lane = tid & 63;
    const int wid4 = (ltid >> 6);    // wave in group
    const int wr   = wid4 >> 1;
    const int wc   = wid4 & 1;
    const int rsel = lane & 15;
    const int kb   = lane >> 4;

    f16* As = (f16*)(smem + wg * 2048);
    f16* Bs = (f16*)(smem + 4096 + wg * 12288);

    int flat = blockIdx.y * gridDim.x + blockIdx.x;   // grid (16, 32)
    int nf   = (flat & 7) * 64 + (flat >> 3);
    const int j0 = (nf >> 5) * 64;
    const int b0 = (nf & 31) * 32;

    f32x4 acc1[3][2], acc2[3][2];
#pragma unroll
    for (int g = 0; g < 3; ++g)
#pragma unroll
        for (int nt = 0; nt < 2; ++nt) { acc1[g][nt] = (f32x4)0.f; acc2[g][nt] = (f32x4)0.f; }

#pragma unroll
    for (int phase = 0; phase < 2; ++phase) {
        const f16* Ap   = phase ? A2 : A1;
        const f16* Btp  = phase ? Bt2 : Bt1;
        const int  ldap = phase ? H_ : lda1;
        const int  ldbp = phase ? H_ : ldb1;
        const int  Kp   = phase ? H_ : K1;
        const int  half = Kp >> 1;
        const int  kend = (wg + 1) * half;

        for (int k0 = wg * half; k0 < kend; k0 += 32) {
            if (ltid < 128)
                STAGE_ROW_T(As, ltid >> 2, Ap + (size_t)(b0 + (ltid >> 2)) * ldap + k0 + (ltid & 3) * 8, ltid);
#pragma unroll
            for (int gg = 0; gg < 3; ++gg)
                STAGE_ROW_T(Bs + gg * 64 * 32, ltid >> 2,
                            Btp + (size_t)(gg * H_ + j0 + (ltid >> 2)) * ldbp + k0 + (ltid & 3) * 8, ltid);
            __syncthreads();

            int arow = wr * 16 + rsel;
            f16x8 af = *(const f16x8*)((char*)As + arow * 64 + ((kb ^ ((arow >> 1) & 3)) << 4));
            f16x8 bf[3][2];
#pragma unroll
            for (int gg = 0; gg < 3; ++gg)
#pragma unroll
                for (int nt = 0; nt < 2; ++nt) {
                    int brow = wc * 32 + nt * 16 + rsel;
                    bf[gg][nt] = *(const f16x8*)((char*)Bs + (gg * 64 + brow) * 64 +
                                                 ((kb ^ ((brow >> 1) & 3)) << 4));
                }
            if (phase == 0) {
#pragma unroll
                for (int gg = 0; gg < 3; ++gg)
#pragma unroll
                    for (int nt = 0; nt < 2; ++nt)
                        acc1[gg][nt] = __builtin_amdgcn_mfma_f32_16x16x32_f16(af, bf[gg][nt], acc1[gg][nt], 0, 0, 0);
            } else {
#pragma unroll
                for (int gg = 0; gg < 3; ++gg)
#pragma unroll
                    for (int nt = 0; nt < 2; ++nt)
                        acc2[gg][nt] = __builtin_amdgcn_mfma_f32_16x16x32_f16(af, bf[gg][nt], acc2[gg][nt], 0, 0, 0);
            }
            __syncthreads();
        }
    }

    // ---- merge wave-group partials (two passes, 24KB each) ----
    f32x4* red = (f32x4*)smem;
    if (wg) {
#pragma unroll
        for (int g = 0; g < 3; ++g)
#pragma unroll
            for (int nt = 0; nt < 2; ++nt) red[ltid * 6 + g * 2 + nt] = acc1[g][nt];
    }
    __syncthreads();
    if (!wg) {
#pragma unroll
        for (int g = 0; g < 3; ++g)
#pragma unroll
            for (int nt = 0; nt < 2; ++nt) acc1[g][nt] += red[ltid * 6 + g * 2 + nt];
    }
    __syncthreads();
    if (wg) {
#pragma unroll
        for (int g = 0; g < 3; ++g)
#pragma unroll
            for (int nt = 0; nt < 2; ++nt) red[ltid * 6 + g * 2 + nt] = acc2[g][nt];
    }
    __syncthreads();

    if (!wg) {
#pragma unroll
        for (int g = 0; g < 3; ++g)
#pragma unroll
            for (int nt = 0; nt < 2; ++nt) acc2[g][nt] += red[ltid * 6 + g * 2 + nt];

        // ---- GRU epilogue (wave-group 0 only) ----
#pragma unroll
        for (int nt = 0; nt < 2; ++nt) {
            int j = j0 + wc * 32 + nt * 16 + rsel;
            float br_i = bih[j],          br_h = bhh[j];
            float bz_i = bih[H_ + j],     bz_h = bhh[H_ + j];
            float bg_i = bih[2 * H_ + j], bg_h = bhh[2 * H_ + j];
#pragma unroll
            for (int q = 0; q < 4; ++q) {
                int row = b0 + wr * 16 + kb * 4 + q;
                float r = sigmoidf_(acc1[0][nt][q] + br_i + acc2[0][nt][q] + br_h);
                float z = sigmoidf_(acc1[1][nt][q] + bz_i + acc2[1][nt][q] + bz_h);
                float g = tanhf(acc1[2][nt][q] + bg_i + r * (acc2[2][nt][q] + bg_h));
                float leak;
                if (MODE == 0) leak = tg_cur[row] * h[(size_t)row * H_ + j];
                else           leak = h[(size_t)row * H_ + j];
                float hn = (1.f - z) * g + z * leak;
                h[(size_t)row * H_ + j] = hn;
                if (MODE == 0) {
                    out_a[(size_t)row * (N_ * H_) + j] = (f16)hn;
                    hs[(size_t)row * H_ + j] = (f16)(tg_next[row] * hn);
                } else {
                    out_a[(size_t)row * H_ + j] = (f16)hn;
                }
            }
        }
    }
}

// ---------------------------------------------------------------------------
// hw2 = h @ W2 (1024^3), split-K in block, 64x64 tile, 512 threads, f32 out.
// ---------------------------------------------------------------------------
__global__ __launch_bounds__(512) void hgemm64_kernel(
    const f16* __restrict__ A, const f16* __restrict__ Bt, float* __restrict__ C)
{
    __shared__ char smem[16384];   // As[2]@0/4096, Bs[2]@8192/12288; reduce 16KB @0

    const int tid  = threadIdx.x;
    const int wg   = tid >> 8;
    const int ltid = tid & 255;
    const int lane = tid & 63;
    const int wid4 = (ltid >> 6);
    const int wr   = wid4 >> 1;
    const int wc   = wid4 & 1;
    const int rsel = lane & 15;
    const int kb   = lane >> 4;

    f16* As = (f16*)(smem + wg * 4096);
    f16* Bs = (f16*)(smem + 8192 + wg * 4096);

    int flat = blockIdx.y * gridDim.x + blockIdx.x;   // grid (16,16)
    int nf   = (flat & 7) * 32 + (flat >> 3);
    const int m0 = (nf >> 4) * 64;
    const int n0 = (nf & 15) * 64;

    f32x4 acc[2][2];
#pragma unroll
    for (int m = 0; m < 2; ++m)
#pragma unroll
        for (int n = 0; n < 2; ++n) acc[m][n] = (f32x4)0.f;

    for (int k0 = wg * 512; k0 < (wg + 1) * 512; k0 += 32) {
        STAGE_ROW_T(As, ltid >> 2, A + (size_t)(m0 + (ltid >> 2)) * H_ + k0 + (ltid & 3) * 8, ltid);
        STAGE_ROW_T(Bs, ltid >> 2, Bt + (size_t)(n0 + (ltid >> 2)) * H_ + k0 + (ltid & 3) * 8, ltid);
        __syncthreads();

        f16x8 af[2], bf[2];
#pragma unroll
        for (int m = 0; m < 2; ++m) {
            int row = wr * 32 + m * 16 + rsel;
            af[m] = *(const f16x8*)((char*)As + row * 64 + ((kb ^ ((row >> 1) & 3)) << 4));
        }
#pragma unroll
        for (int nt = 0; nt < 2; ++nt) {
            int row = wc * 32 + nt * 16 + rsel;
            bf[nt] = *(const f16x8*)((char*)Bs + row * 64 + ((kb ^ ((row >> 1) & 3)) << 4));
        }
#pragma unroll
        for (int m = 0; m < 2; ++m)
#pragma unroll
            for (int nt = 0; nt < 2; ++nt)
                acc[m][nt] = __builtin_amdgcn_mfma_f32_16x16x32_f16(af[m], bf[nt], acc[m][nt], 0, 0, 0);
        __syncthreads();
    }

    f32x4* red = (f32x4*)smem;
    if (wg) {
#pragma unroll
        for (int m = 0; m < 2; ++m)
#pragma unroll
            for (int nt = 0; nt < 2; ++nt) red[ltid * 4 + m * 2 + nt] = acc[m][nt];
    }
    __syncthreads();
    if (!wg) {
#pragma unroll
        for (int m = 0; m < 2; ++m)
#pragma unroll
            for (int nt = 0; nt < 2; ++nt) {
                acc[m][nt] += red[ltid * 4 + m * 2 + nt];
                int col = n0 + wc * 32 + nt * 16 + rsel;
#pragma unroll
                for (int q = 0; q < 4; ++q) {
                    int row = m0 + wr * 32 + m * 16 + kb * 4 + q;
                    C[(size_t)row * H_ + col] = acc[m][nt][q];
                }
            }
    }
}

// ---------------------------------------------------------------------------
// Decoder init
// ---------------------------------------------------------------------------
__global__ void dec_init_kernel(float* __restrict__ h, f16* __restrict__ hs,
                                const f16* __restrict__ he, const int* __restrict__ idx)
{
    int i = blockIdx.x * blockDim.x + threadIdx.x;
    int b = i >> 10;
    int j = i & (H_ - 1);
    float v0 = (float)he[(size_t)b * N_ * H_ + (size_t)idx[b * N_] * H_ + j];
    h[i]  = v0;
    hs[i] = (f16)v0;
}

__global__ void init_input_kernel(f16* __restrict__ inp, const float* __restrict__ tok)
{
    int i = blockIdx.x * blockDim.x + threadIdx.x;
    inp[i] = (f16)tok[i & (I_ - 1)];
}

// ---------------------------------------------------------------------------
// Attention (+ next-step mix). One block per b, 256 threads.
// thread = (n = tid>>4, k-chunk c = tid&15, 64 k each); 16-lane shfl reduce.
// ---------------------------------------------------------------------------
template <int MIX>
__global__ __launch_bounds__(256) void attn_kernel(
    const f16*   __restrict__ w1xe,
    const float* __restrict__ hw2,
    const float* __restrict__ v,
    const float* __restrict__ phis,
    const f16*   __restrict__ in16,
    float* __restrict__ out,
    f16*   __restrict__ inp_step,
    int t,
    const float* __restrict__ tg_next,
    const int*   __restrict__ idx_next,
    const f16*   __restrict__ he,
    float* __restrict__ h,
    f16*   __restrict__ hs,
    const float* __restrict__ tok)
{
    int b   = blockIdx.x;
    int tid = threadIdx.x;
    __shared__ float hw2s[H_];
    __shared__ float vs[H_];
    __shared__ float un[N_];
    __shared__ float attns[N_];

    for (int k = tid; k < H_; k += 256) {
        hw2s[k] = hw2[(size_t)b * H_ + k];
        vs[k]   = v[k];
    }
    __syncthreads();

    {
        int n = tid >> 4, c = tid & 15;
        const f16* wrow = w1xe + ((size_t)(b * N_ + n)) * H_ + c * 64;
        float s = 0.f;
#pragma unroll
        for (int u8 = 0; u8 < 8; ++u8) {
            f16x8 wv = *(const f16x8*)(wrow + u8 * 8);
#pragma unroll
            for (int e = 0; e < 8; ++e) {
                int k = c * 64 + u8 * 8 + e;
                s += tanhf((float)wv[e] + hw2s[k]) * vs[k];
            }
        }
#pragma unroll
        for (int off = 8; off; off >>= 1) s += __shfl_down(s, off, 16);
        if (c == 0) un[n] = s;
    }
    __syncthreads();

    if (tid < N_) {
        float mk = phis[(size_t)b * N_ * N_ + t * N_ + tid];
        float um = un[tid] * mk;
        float m = um;
#pragma unroll
        for (int off = 1; off < 16; off <<= 1) m = fmaxf(m, __shfl_xor(m, off, 16));
        float e = expf(um - m) * mk;
        float ssum = e;
#pragma unroll
        for (int off = 1; off < 16; off <<= 1) ssum += __shfl_xor(ssum, off, 16);
        float a = e / ssum;
        attns[tid] = a;
        out[(size_t)b * N_ * N_ + t * N_ + tid] = a;
    }
    __syncthreads();

    float acc = 0.f;
#pragma unroll
    for (int n = 0; n < N_; ++n)
        acc += attns[n] * (float)in16[((size_t)b * N_ + n) * I_ + tid];

    if (MIX) {
        float tn = tg_next[b];
        inp_step[(size_t)b * I_ + tid] = (f16)(tn * acc + (1.f - tn) * tok[tid]);
        int id = idx_next[b * N_];
        for (int j = tid; j < H_; j += 256) {
            float ih = (float)he[(size_t)b * N_ * H_ + (size_t)id * H_ + j];
            float hm = tn * h[(size_t)b * H_ + j] + (1.f - tn) * ih;
            h[(size_t)b * H_ + j]  = hm;
            hs[(size_t)b * H_ + j] = (f16)hm;
        }
    } else {
        inp_step[(size_t)b * I_ + tid] = (f16)acc;
    }
}

// ---------------------------------------------------------------------------
// Launcher
// ---------------------------------------------------------------------------
extern "C" void kernel_launch(void* const* d_in, const int* in_sizes, int n_in,
                              void* d_out, int out_size, void* d_ws, size_t ws_size,
                              hipStream_t stream)
{
    const float* input      = (const float*)d_in[0];
    const float* phis       = (const float*)d_in[1];
    const float* init_token = (const float*)d_in[2];
    const float* W1         = (const float*)d_in[3];
    const float* W2         = (const float*)d_in[4];
    const float* v          = (const float*)d_in[5];
    const float* Wih_e      = (const float*)d_in[6];
    const float* Whh_e      = (const float*)d_in[7];
    const float* bih_e      = (const float*)d_in[8];
    const float* bhh_e      = (const float*)d_in[9];
    const float* Wih_d      = (const float*)d_in[10];
    const float* Whh_d      = (const float*)d_in[11];
    const float* bih_d      = (const float*)d_in[12];
    const float* bhh_d      = (const float*)d_in[13];
    float* out = (float*)d_out;

    char* p = (char*)d_ws;
    f16*  he16    = (f16*)p;  p += (size_t)B_ * N_ * H_ * 2;
    f16*  w1xe16  = (f16*)p;  p += (size_t)B_ * N_ * H_ * 2;
    float* h      = (float*)p; p += (size_t)B_ * H_ * 4;
    f16*  hs16    = (f16*)p;  p += (size_t)B_ * H_ * 2;
    f16*  hc16    = (f16*)p;  p += (size_t)B_ * H_ * 2;
    f16*  inp16   = (f16*)p;  p += (size_t)B_ * I_ * 2;
    float* hw2    = (float*)p; p += (size_t)B_ * H_ * 4;
    f16*  in16    = (f16*)p;  p += (size_t)B_ * N_ * I_ * 2;
    f16*  Wih_e16 = (f16*)p;  p += (size_t)H3_ * I_ * 2;
    f16*  Whh_e16 = (f16*)p;  p += (size_t)H3_ * H_ * 2;
    f16*  Wih_d16 = (f16*)p;  p += (size_t)H3_ * I_ * 2;
    f16*  Whh_d16 = (f16*)p;  p += (size_t)H3_ * H_ * 2;
    f16*  W1t16   = (f16*)p;  p += (size_t)H_ * H_ * 2;
    f16*  W2t16   = (f16*)p;  p += (size_t)H_ * H_ * 2;
    float* tg     = (float*)p; p += (size_t)17 * B_ * 4;
    int*   idx    = (int*)p;   p += (size_t)B_ * N_ * 4;

    const int BHBLK = (B_ * H_) / 256;
    const int BIBLK = (B_ * I_) / 256;
    const dim3 gru_grid(16, 32);

    precompute_kernel<<<4, 256, 0, stream>>>(phis, tg, idx);

    cast_kernel<<<(B_ * N_ * I_) / 256, 256, 0, stream>>>(input, in16, B_ * N_ * I_);
    cast4_kernel<<<(2 * (H3_ * I_ + H3_ * H_)) / 256, 256, 0, stream>>>(
        Wih_e, Wih_e16, H3_ * I_, Whh_e, Whh_e16, H3_ * H_,
        Wih_d, Wih_d16, H3_ * I_, Whh_d, Whh_d16, H3_ * H_);
    transpose_cast2_kernel<<<dim3(32, 32, 2), 256, 0, stream>>>(W1, W1t16, W2, W2t16);

    // ---------------- encoder ----------------
    hipMemsetAsync(h, 0, (size_t)B_ * H_ * 4, stream);
    hipMemsetAsync(hs16, 0, (size_t)B_ * H_ * 2, stream);
    for (int t = 0; t < N_; ++t) {
        gru_fused_kernel<0><<<gru_grid, 512, 0, stream>>>(
            in16 + (size_t)t * I_, N_ * I_, Wih_e16, I_, I_,
            hs16, Whh_e16, bih_e, bhh_e, h,
            tg + (size_t)t * B_, tg + (size_t)(t + 1) * B_,
            he16 + (size_t)t * H_, hs16);
    }

    // ---------------- W1xe = he @ W1 (f16 out) ----------------
    hgemm_kernel<f16><<<dim3(H_ / 128, (B_ * N_) / 128), 256, 0, stream>>>(
        he16, H_, W1t16, H_, w1xe16, H_, H_);

    // ---------------- decoder ----------------
    dec_init_kernel<<<BHBLK, 256, 0, stream>>>(h, hs16, he16, idx);
    init_input_kernel<<<BIBLK, 256, 0, stream>>>(inp16, init_token);
    for (int t = 0; t < N_; ++t) {
        gru_fused_kernel<1><<<gru_grid, 512, 0, stream>>>(
            inp16, I_, Wih_d16, I_, I_,
            hs16, Whh_d16, bih_d, bhh_d, h,
            nullptr, nullptr, hc16, nullptr);
        hgemm64_kernel<<<dim3(16, 16), 512, 0, stream>>>(hc16, W2t16, hw2);
        if (t < N_ - 1)
            attn_kernel<1><<<B_, 256, 0, stream>>>(
                w1xe16, hw2, v, phis, in16, out, inp16, t,
                tg + (size_t)(t + 1) * B_, idx + (t + 1), he16, h, hs16, init_token);
        else
            attn_kernel<0><<<B_, 256, 0, stream>>>(
                w1xe16, hw2, v, phis, in16, out, inp16, t,
                tg, idx, he16, h, hs16, init_token);
    }
}

// Round 6
// 1597.295 us; speedup vs baseline: 3.8877x; 1.1435x over previous
//
#include <hip/hip_runtime.h>
#include <math.h>

#define B_  1024
#define N_  16
#define I_  256
#define H_  1024
#define H3_ 3072

typedef _Float16 f16;
typedef _Float16 f16x4 __attribute__((ext_vector_type(4)));
typedef _Float16 f16x8 __attribute__((ext_vector_type(8)));
typedef float    f32x4 __attribute__((ext_vector_type(4)));

__device__ __forceinline__ float sigmoidf_(float x) { return 1.f / (1.f + expf(-x)); }

// ---------------------------------------------------------------------------
// Precompute t_gate (17,B) and idx_seq (B,N)
// ---------------------------------------------------------------------------
__global__ void precompute_kernel(const float* __restrict__ phis,
                                  float* __restrict__ tg,
                                  int* __restrict__ idx)
{
    int b = blockIdx.x * blockDim.x + threadIdx.x;
    if (b >= B_) return;
    tg[b] = 1.0f;
    for (int t = 1; t < N_; ++t)
        tg[t * B_ + b] = phis[(size_t)b * N_ * N_ + t * N_ + (t - 1)];
    tg[16 * B_ + b] = 0.0f;
    for (int t = 0; t < N_; ++t) {
        float ns = 0.f;
        for (int k = 0; k < N_; ++k) ns += phis[(size_t)b * N_ * N_ + t * N_ + k];
        int nsi = (int)(ns + 0.5f);
        idx[b * N_ + t] = (nsi + t - 1) % N_;
    }
}

// ---------------------------------------------------------------------------
// Casts
// ---------------------------------------------------------------------------
__global__ void cast_kernel(const float* __restrict__ in, f16* __restrict__ out, int n)
{
    int i = blockIdx.x * blockDim.x + threadIdx.x;
    if (i < n) out[i] = (f16)in[i];
}

__global__ void cast4_kernel(const float* __restrict__ s0, f16* __restrict__ d0, int n0,
                             const float* __restrict__ s1, f16* __restrict__ d1, int n1,
                             const float* __restrict__ s2, f16* __restrict__ d2, int n2,
                             const float* __restrict__ s3, f16* __restrict__ d3, int n3)
{
    int i = blockIdx.x * blockDim.x + threadIdx.x;
    int T0 = n0, T1 = T0 + n1, T2 = T1 + n2, T3 = T2 + n3;
    if (i < T0) d0[i] = (f16)s0[i];
    else if (i < T1) d1[i - T0] = (f16)s1[i - T0];
    else if (i < T2) d2[i - T1] = (f16)s2[i - T1];
    else if (i < T3) d3[i - T2] = (f16)s3[i - T2];
}

__global__ __launch_bounds__(256) void transpose_cast2_kernel(
    const float* __restrict__ in0, f16* __restrict__ out0,
    const float* __restrict__ in1, f16* __restrict__ out1)
{
    const float* in  = blockIdx.z ? in1 : in0;
    f16*        outp = blockIdx.z ? out1 : out0;
    __shared__ float tile[32][33];
    int bx = blockIdx.x * 32, by = blockIdx.y * 32;
    int tx = threadIdx.x & 31, ty = threadIdx.x >> 5;
#pragma unroll
    for (int r = 0; r < 32; r += 8)
        tile[ty + r][tx] = in[(size_t)(by + ty + r) * H_ + bx + tx];
    __syncthreads();
#pragma unroll
    for (int r = 0; r < 32; r += 8)
        outp[(size_t)(bx + ty + r) * H_ + by + tx] = (f16)tile[tx][ty + r];
}

// ---------------------------------------------------------------------------
// LDS layout (verified r3): row = 64B = 4 groups of 16B; group g holds
// k = {4g..4g+3, 16+4g..16+4g+3}; XOR swizzle by ((row>>1)&3).
// ---------------------------------------------------------------------------
#define STAGE_ROW_T(dst, rowexpr, srcptr, t)                                   \
    {                                                                          \
        int row_ = rowexpr, s_ = (t) & 3;                                      \
        int key_ = (row_ >> 1) & 3;                                            \
        int g0_  = (((s_ & 1) * 2 + 0) ^ key_);                                \
        int g1_  = (((s_ & 1) * 2 + 1) ^ key_);                                \
        f16x8 vv_ = *(const f16x8*)(srcptr);                                   \
        f16x4 lo_ = {vv_[0], vv_[1], vv_[2], vv_[3]};                          \
        f16x4 hi_ = {vv_[4], vv_[5], vv_[6], vv_[7]};                          \
        *(f16x4*)((char*)(dst) + row_ * 64 + g0_ * 16 + (s_ >> 1) * 8) = lo_;  \
        *(f16x4*)((char*)(dst) + row_ * 64 + g1_ * 16 + (s_ >> 1) * 8) = hi_;  \
    }

// ---------------------------------------------------------------------------
// 128x128 MFMA GEMM (W1xe): C = A @ Bt^T, f16 out, XCD-chunked swizzle.
// ---------------------------------------------------------------------------
template <typename OutT>
__global__ __launch_bounds__(256) void hgemm_kernel(
    const f16* __restrict__ A, int lda,
    const f16* __restrict__ Bt, int ldb,
    OutT* __restrict__ C, int ldc, int K)
{
    __shared__ f16 As[128 * 32];
    __shared__ f16 Bs[128 * 32];

    const int tid  = threadIdx.x;
    const int lane = tid & 63;
    const int wid  = tid >> 6;
    const int wr   = wid >> 1;
    const int wc   = wid & 1;
    const int rsel = lane & 15;
    const int kb   = lane >> 4;

    int flat = blockIdx.y * gridDim.x + blockIdx.x;
    int nwg  = gridDim.x * gridDim.y;
    int cpx  = nwg >> 3;
    int nf   = (flat & 7) * cpx + (flat >> 3);
    const int n0 = (int)(nf % gridDim.x) * 128;
    const int m0 = (int)(nf / gridDim.x) * 128;

    f32x4 acc[4][4];
#pragma unroll
    for (int m = 0; m < 4; ++m)
#pragma unroll
        for (int n = 0; n < 4; ++n) acc[m][n] = (f32x4)0.f;

    for (int k0 = 0; k0 < K; k0 += 32) {
#pragma unroll
        for (int r = 0; r < 2; ++r) {
            int li = r * 256 + tid;
            STAGE_ROW_T(As, li >> 2, A + (size_t)(m0 + (li >> 2)) * lda + k0 + (tid & 3) * 8, tid);
            STAGE_ROW_T(Bs, li >> 2, Bt + (size_t)(n0 + (li >> 2)) * ldb + k0 + (tid & 3) * 8, tid);
        }
        __syncthreads();

        f16x8 af[4], bf[4];
#pragma unroll
        for (int m = 0; m < 4; ++m) {
            int row = wr * 64 + m * 16 + rsel;
            af[m] = *(const f16x8*)((char*)As + row * 64 + ((kb ^ ((row >> 1) & 3)) << 4));
        }
#pragma unroll
        for (int n = 0; n < 4; ++n) {
            int row = wc * 64 + n * 16 + rsel;
            bf[n] = *(const f16x8*)((char*)Bs + row * 64 + ((kb ^ ((row >> 1) & 3)) << 4));
        }
#pragma unroll
        for (int m = 0; m < 4; ++m)
#pragma unroll
            for (int n = 0; n < 4; ++n)
                acc[m][n] = __builtin_amdgcn_mfma_f32_16x16x32_f16(af[m], bf[n], acc[m][n], 0, 0, 0);
        __syncthreads();
    }

#pragma unroll
    for (int m = 0; m < 4; ++m) {
        int row0 = m0 + wr * 64 + m * 16 + kb * 4;
#pragma unroll
        for (int n = 0; n < 4; ++n) {
            int col = n0 + wc * 64 + n * 16 + rsel;
#pragma unroll
            for (int r = 0; r < 4; ++r)
                C[(size_t)(row0 + r) * ldc + col] = (OutT)acc[m][n][r];
        }
    }
}

// ---------------------------------------------------------------------------
// Fused GEMM + GRU, split-K in block. 512 threads = 2 wave-groups of 4 waves.
// ---------------------------------------------------------------------------
template <int MODE>
__global__ __launch_bounds__(512) void gru_fused_kernel(
    const f16* __restrict__ A1, int lda1,
    const f16* __restrict__ Bt1, int ldb1, int K1,
    const f16* __restrict__ A2,
    const f16* __restrict__ Bt2,
    const float* __restrict__ bih, const float* __restrict__ bhh,
    float* __restrict__ h,
    const float* __restrict__ tg_cur,
    const float* __restrict__ tg_next,
    f16* __restrict__ out_a,
    f16* __restrict__ hs)
{
    __shared__ char smem[28672];

    const int tid  = threadIdx.x;
    const int wg   = tid >> 8;
    const int ltid = tid & 255;
    const int lane = tid & 63;
    const int wid4 = (ltid >> 6);
    const int wr   = wid4 >> 1;
    const int wc   = wid4 & 1;
    const int rsel = lane & 15;
    const int kb   = lane >> 4;

    f16* As = (f16*)(smem + wg * 2048);
    f16* Bs = (f16*)(smem + 4096 + wg * 12288);

    int flat = blockIdx.y * gridDim.x + blockIdx.x;
    int nf   = (flat & 7) * 64 + (flat >> 3);
    const int j0 = (nf >> 5) * 64;
    const int b0 = (nf & 31) * 32;

    f32x4 acc1[3][2], acc2[3][2];
#pragma unroll
    for (int g = 0; g < 3; ++g)
#pragma unroll
        for (int nt = 0; nt < 2; ++nt) { acc1[g][nt] = (f32x4)0.f; acc2[g][nt] = (f32x4)0.f; }

#pragma unroll
    for (int phase = 0; phase < 2; ++phase) {
        const f16* Ap   = phase ? A2 : A1;
        const f16* Btp  = phase ? Bt2 : Bt1;
        const int  ldap = phase ? H_ : lda1;
        const int  ldbp = phase ? H_ : ldb1;
        const int  Kp   = phase ? H_ : K1;
        const int  half = Kp >> 1;
        const int  kend = (wg + 1) * half;

        for (int k0 = wg * half; k0 < kend; k0 += 32) {
            if (ltid < 128)
                STAGE_ROW_T(As, ltid >> 2, Ap + (size_t)(b0 + (ltid >> 2)) * ldap + k0 + (ltid & 3) * 8, ltid);
#pragma unroll
            for (int gg = 0; gg < 3; ++gg)
                STAGE_ROW_T(Bs + gg * 64 * 32, ltid >> 2,
                            Btp + (size_t)(gg * H_ + j0 + (ltid >> 2)) * ldbp + k0 + (ltid & 3) * 8, ltid);
            __syncthreads();

            int arow = wr * 16 + rsel;
            f16x8 af = *(const f16x8*)((char*)As + arow * 64 + ((kb ^ ((arow >> 1) & 3)) << 4));
            f16x8 bf[3][2];
#pragma unroll
            for (int gg = 0; gg < 3; ++gg)
#pragma unroll
                for (int nt = 0; nt < 2; ++nt) {
                    int brow = wc * 32 + nt * 16 + rsel;
                    bf[gg][nt] = *(const f16x8*)((char*)Bs + (gg * 64 + brow) * 64 +
                                                 ((kb ^ ((brow >> 1) & 3)) << 4));
                }
            if (phase == 0) {
#pragma unroll
                for (int gg = 0; gg < 3; ++gg)
#pragma unroll
                    for (int nt = 0; nt < 2; ++nt)
                        acc1[gg][nt] = __builtin_amdgcn_mfma_f32_16x16x32_f16(af, bf[gg][nt], acc1[gg][nt], 0, 0, 0);
            } else {
#pragma unroll
                for (int gg = 0; gg < 3; ++gg)
#pragma unroll
                    for (int nt = 0; nt < 2; ++nt)
                        acc2[gg][nt] = __builtin_amdgcn_mfma_f32_16x16x32_f16(af, bf[gg][nt], acc2[gg][nt], 0, 0, 0);
            }
            __syncthreads();
        }
    }

    f32x4* red = (f32x4*)smem;
    if (wg) {
#pragma unroll
        for (int g = 0; g < 3; ++g)
#pragma unroll
            for (int nt = 0; nt < 2; ++nt) red[ltid * 6 + g * 2 + nt] = acc1[g][nt];
    }
    __syncthreads();
    if (!wg) {
#pragma unroll
        for (int g = 0; g < 3; ++g)
#pragma unroll
            for (int nt = 0; nt < 2; ++nt) acc1[g][nt] += red[ltid * 6 + g * 2 + nt];
    }
    __syncthreads();
    if (wg) {
#pragma unroll
        for (int g = 0; g < 3; ++g)
#pragma unroll
            for (int nt = 0; nt < 2; ++nt) red[ltid * 6 + g * 2 + nt] = acc2[g][nt];
    }
    __syncthreads();

    if (!wg) {
#pragma unroll
        for (int g = 0; g < 3; ++g)
#pragma unroll
            for (int nt = 0; nt < 2; ++nt) acc2[g][nt] += red[ltid * 6 + g * 2 + nt];

#pragma unroll
        for (int nt = 0; nt < 2; ++nt) {
            int j = j0 + wc * 32 + nt * 16 + rsel;
            float br_i = bih[j],          br_h = bhh[j];
            float bz_i = bih[H_ + j],     bz_h = bhh[H_ + j];
            float bg_i = bih[2 * H_ + j], bg_h = bhh[2 * H_ + j];
#pragma unroll
            for (int q = 0; q < 4; ++q) {
                int row = b0 + wr * 16 + kb * 4 + q;
                float r = sigmoidf_(acc1[0][nt][q] + br_i + acc2[0][nt][q] + br_h);
                float z = sigmoidf_(acc1[1][nt][q] + bz_i + acc2[1][nt][q] + bz_h);
                float g = tanhf(acc1[2][nt][q] + bg_i + r * (acc2[2][nt][q] + bg_h));
                float leak;
                if (MODE == 0) leak = tg_cur[row] * h[(size_t)row * H_ + j];
                else           leak = h[(size_t)row * H_ + j];
                float hn = (1.f - z) * g + z * leak;
                h[(size_t)row * H_ + j] = hn;
                if (MODE == 0) {
                    out_a[(size_t)row * (N_ * H_) + j] = (f16)hn;
                    hs[(size_t)row * H_ + j] = (f16)(tg_next[row] * hn);
                } else {
                    out_a[(size_t)row * H_ + j] = (f16)hn;
                }
            }
        }
    }
}

// ---------------------------------------------------------------------------
// hw2 = h @ W2 (1024^3), split-K in block, 64x64 tile, 512 threads, f32 out.
// ---------------------------------------------------------------------------
__global__ __launch_bounds__(512) void hgemm64_kernel(
    const f16* __restrict__ A, const f16* __restrict__ Bt, float* __restrict__ C)
{
    __shared__ char smem[16384];

    const int tid  = threadIdx.x;
    const int wg   = tid >> 8;
    const int ltid = tid & 255;
    const int lane = tid & 63;
    const int wid4 = (ltid >> 6);
    const int wr   = wid4 >> 1;
    const int wc   = wid4 & 1;
    const int rsel = lane & 15;
    const int kb   = lane >> 4;

    f16* As = (f16*)(smem + wg * 4096);
    f16* Bs = (f16*)(smem + 8192 + wg * 4096);

    int flat = blockIdx.y * gridDim.x + blockIdx.x;
    int nf   = (flat & 7) * 32 + (flat >> 3);
    const int m0 = (nf >> 4) * 64;
    const int n0 = (nf & 15) * 64;

    f32x4 acc[2][2];
#pragma unroll
    for (int m = 0; m < 2; ++m)
#pragma unroll
        for (int n = 0; n < 2; ++n) acc[m][n] = (f32x4)0.f;

    for (int k0 = wg * 512; k0 < (wg + 1) * 512; k0 += 32) {
        STAGE_ROW_T(As, ltid >> 2, A + (size_t)(m0 + (ltid >> 2)) * H_ + k0 + (ltid & 3) * 8, ltid);
        STAGE_ROW_T(Bs, ltid >> 2, Bt + (size_t)(n0 + (ltid >> 2)) * H_ + k0 + (ltid & 3) * 8, ltid);
        __syncthreads();

        f16x8 af[2], bf[2];
#pragma unroll
        for (int m = 0; m < 2; ++m) {
            int row = wr * 32 + m * 16 + rsel;
            af[m] = *(const f16x8*)((char*)As + row * 64 + ((kb ^ ((row >> 1) & 3)) << 4));
        }
#pragma unroll
        for (int nt = 0; nt < 2; ++nt) {
            int row = wc * 32 + nt * 16 + rsel;
            bf[nt] = *(const f16x8*)((char*)Bs + row * 64 + ((kb ^ ((row >> 1) & 3)) << 4));
        }
#pragma unroll
        for (int m = 0; m < 2; ++m)
#pragma unroll
            for (int nt = 0; nt < 2; ++nt)
                acc[m][nt] = __builtin_amdgcn_mfma_f32_16x16x32_f16(af[m], bf[nt], acc[m][nt], 0, 0, 0);
        __syncthreads();
    }

    f32x4* red = (f32x4*)smem;
    if (wg) {
#pragma unroll
        for (int m = 0; m < 2; ++m)
#pragma unroll
            for (int nt = 0; nt < 2; ++nt) red[ltid * 4 + m * 2 + nt] = acc[m][nt];
    }
    __syncthreads();
    if (!wg) {
#pragma unroll
        for (int m = 0; m < 2; ++m)
#pragma unroll
            for (int nt = 0; nt < 2; ++nt) {
                acc[m][nt] += red[ltid * 4 + m * 2 + nt];
                int col = n0 + wc * 32 + nt * 16 + rsel;
#pragma unroll
                for (int q = 0; q < 4; ++q) {
                    int row = m0 + wr * 32 + m * 16 + kb * 4 + q;
                    C[(size_t)row * H_ + col] = acc[m][nt][q];
                }
            }
    }
}

// ---------------------------------------------------------------------------
// Decoder init
// ---------------------------------------------------------------------------
__global__ void dec_init_kernel(float* __restrict__ h, f16* __restrict__ hs,
                                const f16* __restrict__ he, const int* __restrict__ idx)
{
    int i = blockIdx.x * blockDim.x + threadIdx.x;
    int b = i >> 10;
    int j = i & (H_ - 1);
    float v0 = (float)he[(size_t)b * N_ * H_ + (size_t)idx[b * N_] * H_ + j];
    h[i]  = v0;
    hs[i] = (f16)v0;
}

__global__ void init_input_kernel(f16* __restrict__ inp, const float* __restrict__ tok)
{
    int i = blockIdx.x * blockDim.x + threadIdx.x;
    inp[i] = (f16)tok[i & (I_ - 1)];
}

// ---------------------------------------------------------------------------
// Attention (+ next-step mix). One block per b, 256 threads.
// Conflict-free LDS: element k = c*64+j stored at [c*68 + j]
//   read phase: lanes c=0..15 at float-stride 68 -> banks (4c+j)%32, 2-way max
//   per-thread j contiguous -> ds_read_b128 (4 floats/read)
// ---------------------------------------------------------------------------
template <int MIX>
__global__ __launch_bounds__(256) void attn_kernel(
    const f16*   __restrict__ w1xe,
    const float* __restrict__ hw2,
    const float* __restrict__ v,
    const float* __restrict__ phis,
    const f16*   __restrict__ in16,
    float* __restrict__ out,
    f16*   __restrict__ inp_step,
    int t,
    const float* __restrict__ tg_next,
    const int*   __restrict__ idx_next,
    const f16*   __restrict__ he,
    float* __restrict__ h,
    f16*   __restrict__ hs,
    const float* __restrict__ tok)
{
    int b   = blockIdx.x;
    int tid = threadIdx.x;
    __shared__ float hw2s[16 * 68];
    __shared__ float vs[16 * 68];
    __shared__ float un[N_];
    __shared__ float attns[N_];

    {
        int k = tid * 4;                 // 256 threads x 4 = 1024
        int c = k >> 6, j = k & 63;
        float4 hv = *(const float4*)(hw2 + (size_t)b * H_ + k);
        float4 vv = *(const float4*)(v + k);
        *(float4*)&hw2s[c * 68 + j] = hv;
        *(float4*)&vs[c * 68 + j]   = vv;
    }
    __syncthreads();

    {
        int n = tid >> 4, c = tid & 15;
        const f16* wrow = w1xe + ((size_t)(b * N_ + n)) * H_ + c * 64;
        const float* hrow = &hw2s[c * 68];
        const float* vrow = &vs[c * 68];
        float s = 0.f;
#pragma unroll
        for (int u8 = 0; u8 < 8; ++u8) {
            f16x8 wv = *(const f16x8*)(wrow + u8 * 8);
            f32x4 h0 = *(const f32x4*)(hrow + u8 * 8);
            f32x4 h1 = *(const f32x4*)(hrow + u8 * 8 + 4);
            f32x4 v0 = *(const f32x4*)(vrow + u8 * 8);
            f32x4 v1 = *(const f32x4*)(vrow + u8 * 8 + 4);
#pragma unroll
            for (int e = 0; e < 4; ++e) {
                s += tanhf((float)wv[e] + h0[e]) * v0[e];
                s += tanhf((float)wv[e + 4] + h1[e]) * v1[e];
            }
        }
#pragma unroll
        for (int off = 8; off; off >>= 1) s += __shfl_down(s, off, 16);
        if (c == 0) un[n] = s;
    }
    __syncthreads();

    if (tid < N_) {
        float mk = phis[(size_t)b * N_ * N_ + t * N_ + tid];
        float um = un[tid] * mk;
        float m = um;
#pragma unroll
        for (int off = 1; off < 16; off <<= 1) m = fmaxf(m, __shfl_xor(m, off, 16));
        float e = expf(um - m) * mk;
        float ssum = e;
#pragma unroll
        for (int off = 1; off < 16; off <<= 1) ssum += __shfl_xor(ssum, off, 16);
        float a = e / ssum;
        attns[tid] = a;
        out[(size_t)b * N_ * N_ + t * N_ + tid] = a;
    }
    __syncthreads();

    float acc = 0.f;
#pragma unroll
    for (int n = 0; n < N_; ++n)
        acc += attns[n] * (float)in16[((size_t)b * N_ + n) * I_ + tid];

    if (MIX) {
        float tn = tg_next[b];
        inp_step[(size_t)b * I_ + tid] = (f16)(tn * acc + (1.f - tn) * tok[tid]);
        int id = idx_next[b * N_];
        int j4 = tid * 4;                // 256 threads x 4 = 1024 = H_
        f16x4 ihv = *(const f16x4*)(he + (size_t)b * N_ * H_ + (size_t)id * H_ + j4);
        float4 hv = *(float4*)(h + (size_t)b * H_ + j4);
        float4 hm;
        f16x4 hsv;
#pragma unroll
        for (int e = 0; e < 4; ++e) {
            float x = tn * (&hv.x)[e] + (1.f - tn) * (float)ihv[e];
            (&hm.x)[e] = x;
            hsv[e] = (f16)x;
        }
        *(float4*)(h + (size_t)b * H_ + j4) = hm;
        *(f16x4*)(hs + (size_t)b * H_ + j4) = hsv;
    } else {
        inp_step[(size_t)b * I_ + tid] = (f16)acc;
    }
}

// ---------------------------------------------------------------------------
// Launcher
// ---------------------------------------------------------------------------
extern "C" void kernel_launch(void* const* d_in, const int* in_sizes, int n_in,
                              void* d_out, int out_size, void* d_ws, size_t ws_size,
                              hipStream_t stream)
{
    const float* input      = (const float*)d_in[0];
    const float* phis       = (const float*)d_in[1];
    const float* init_token = (const float*)d_in[2];
    const float* W1         = (const float*)d_in[3];
    const float* W2         = (const float*)d_in[4];
    const float* v          = (const float*)d_in[5];
    const float* Wih_e      = (const float*)d_in[6];
    const float* Whh_e      = (const float*)d_in[7];
    const float* bih_e      = (const float*)d_in[8];
    const float* bhh_e      = (const float*)d_in[9];
    const float* Wih_d      = (const float*)d_in[10];
    const float* Whh_d      = (const float*)d_in[11];
    const float* bih_d      = (const float*)d_in[12];
    const float* bhh_d      = (const float*)d_in[13];
    float* out = (float*)d_out;

    char* p = (char*)d_ws;
    f16*  he16    = (f16*)p;  p += (size_t)B_ * N_ * H_ * 2;
    f16*  w1xe16  = (f16*)p;  p += (size_t)B_ * N_ * H_ * 2;
    float* h      = (float*)p; p += (size_t)B_ * H_ * 4;
    f16*  hs16    = (f16*)p;  p += (size_t)B_ * H_ * 2;
    f16*  hc16    = (f16*)p;  p += (size_t)B_ * H_ * 2;
    f16*  inp16   = (f16*)p;  p += (size_t)B_ * I_ * 2;
    float* hw2    = (float*)p; p += (size_t)B_ * H_ * 4;
    f16*  in16    = (f16*)p;  p += (size_t)B_ * N_ * I_ * 2;
    f16*  Wih_e16 = (f16*)p;  p += (size_t)H3_ * I_ * 2;
    f16*  Whh_e16 = (f16*)p;  p += (size_t)H3_ * H_ * 2;
    f16*  Wih_d16 = (f16*)p;  p += (size_t)H3_ * I_ * 2;
    f16*  Whh_d16 = (f16*)p;  p += (size_t)H3_ * H_ * 2;
    f16*  W1t16   = (f16*)p;  p += (size_t)H_ * H_ * 2;
    f16*  W2t16   = (f16*)p;  p += (size_t)H_ * H_ * 2;
    float* tg     = (float*)p; p += (size_t)17 * B_ * 4;
    int*   idx    = (int*)p;   p += (size_t)B_ * N_ * 4;

    const int BHBLK = (B_ * H_) / 256;
    const int BIBLK = (B_ * I_) / 256;
    const dim3 gru_grid(16, 32);

    precompute_kernel<<<4, 256, 0, stream>>>(phis, tg, idx);

    cast_kernel<<<(B_ * N_ * I_) / 256, 256, 0, stream>>>(input, in16, B_ * N_ * I_);
    cast4_kernel<<<(2 * (H3_ * I_ + H3_ * H_)) / 256, 256, 0, stream>>>(
        Wih_e, Wih_e16, H3_ * I_, Whh_e, Whh_e16, H3_ * H_,
        Wih_d, Wih_d16, H3_ * I_, Whh_d, Whh_d16, H3_ * H_);
    transpose_cast2_kernel<<<dim3(32, 32, 2), 256, 0, stream>>>(W1, W1t16, W2, W2t16);

    // ---------------- encoder ----------------
    hipMemsetAsync(h, 0, (size_t)B_ * H_ * 4, stream);
    hipMemsetAsync(hs16, 0, (size_t)B_ * H_ * 2, stream);
    for (int t = 0; t < N_; ++t) {
        gru_fused_kernel<0><<<gru_grid, 512, 0, stream>>>(
            in16 + (size_t)t * I_, N_ * I_, Wih_e16, I_, I_,
            hs16, Whh_e16, bih_e, bhh_e, h,
            tg + (size_t)t * B_, tg + (size_t)(t + 1) * B_,
            he16 + (size_t)t * H_, hs16);
    }

    // ---------------- W1xe = he @ W1 (f16 out) ----------------
    hgemm_kernel<f16><<<dim3(H_ / 128, (B_ * N_) / 128), 256, 0, stream>>>(
        he16, H_, W1t16, H_, w1xe16, H_, H_);

    // ---------------- decoder ----------------
    dec_init_kernel<<<BHBLK, 256, 0, stream>>>(h, hs16, he16, idx);
    init_input_kernel<<<BIBLK, 256, 0, stream>>>(inp16, init_token);
    for (int t = 0; t < N_; ++t) {
        gru_fused_kernel<1><<<gru_grid, 512, 0, stream>>>(
            inp16, I_, Wih_d16, I_, I_,
            hs16, Whh_d16, bih_d, bhh_d, h,
            nullptr, nullptr, hc16, nullptr);
        hgemm64_kernel<<<dim3(16, 16), 512, 0, stream>>>(hc16, W2t16, hw2);
        if (t < N_ - 1)
            attn_kernel<1><<<B_, 256, 0, stream>>>(
                w1xe16, hw2, v, phis, in16, out, inp16, t,
                tg + (size_t)(t + 1) * B_, idx + (t + 1), he16, h, hs16, init_token);
        else
            attn_kernel<0><<<B_, 256, 0, stream>>>(
                w1xe16, hw2, v, phis, in16, out, inp16, t,
                tg, idx, he16, h, hs16, init_token);
    }
}

// Round 7
// 1498.932 us; speedup vs baseline: 4.1428x; 1.0656x over previous
//
#include <hip/hip_runtime.h>
#include <math.h>

#define B_  1024
#define N_  16
#define I_  256
#define H_  1024
#define H3_ 3072

typedef _Float16 f16;
typedef _Float16 f16x4 __attribute__((ext_vector_type(4)));
typedef _Float16 f16x8 __attribute__((ext_vector_type(8)));
typedef float    f32x4 __attribute__((ext_vector_type(4)));

__device__ __forceinline__ float sigmoidf_(float x) { return 1.f / (1.f + expf(-x)); }

// LDS layout (verified r3): row = 64B = 4 groups of 16B; group g holds
// k = {4g..4g+3, 16+4g..16+4g+3}; XOR swizzle by ((row>>1)&3).
// One ds_read_b128 at group (lane>>4)^key = full 8-elem mfma_16x16x32 frag.
__device__ __forceinline__ void lds_write_row(f16* dst, int row, int s, f16x8 vv)
{
    int key = (row >> 1) & 3;
    int g0  = (((s & 1) * 2 + 0) ^ key);
    int g1  = (((s & 1) * 2 + 1) ^ key);
    f16x4 lo = {vv[0], vv[1], vv[2], vv[3]};
    f16x4 hi = {vv[4], vv[5], vv[6], vv[7]};
    *(f16x4*)((char*)dst + row * 64 + g0 * 16 + (s >> 1) * 8) = lo;
    *(f16x4*)((char*)dst + row * 64 + g1 * 16 + (s >> 1) * 8) = hi;
}

// ---------------------------------------------------------------------------
// Precompute t_gate (17,B) and idx_seq (B,N)
// ---------------------------------------------------------------------------
__global__ void precompute_kernel(const float* __restrict__ phis,
                                  float* __restrict__ tg,
                                  int* __restrict__ idx)
{
    int b = blockIdx.x * blockDim.x + threadIdx.x;
    if (b >= B_) return;
    tg[b] = 1.0f;
    for (int t = 1; t < N_; ++t)
        tg[t * B_ + b] = phis[(size_t)b * N_ * N_ + t * N_ + (t - 1)];
    tg[16 * B_ + b] = 0.0f;
    for (int t = 0; t < N_; ++t) {
        float ns = 0.f;
        for (int k = 0; k < N_; ++k) ns += phis[(size_t)b * N_ * N_ + t * N_ + k];
        int nsi = (int)(ns + 0.5f);
        idx[b * N_ + t] = (nsi + t - 1) % N_;
    }
}

// ---------------------------------------------------------------------------
// Casts
// ---------------------------------------------------------------------------
__global__ void cast_kernel(const float* __restrict__ in, f16* __restrict__ out, int n)
{
    int i = blockIdx.x * blockDim.x + threadIdx.x;
    if (i < n) out[i] = (f16)in[i];
}

__global__ void cast4_kernel(const float* __restrict__ s0, f16* __restrict__ d0, int n0,
                             const float* __restrict__ s1, f16* __restrict__ d1, int n1,
                             const float* __restrict__ s2, f16* __restrict__ d2, int n2,
                             const float* __restrict__ s3, f16* __restrict__ d3, int n3)
{
    int i = blockIdx.x * blockDim.x + threadIdx.x;
    int T0 = n0, T1 = T0 + n1, T2 = T1 + n2, T3 = T2 + n3;
    if (i < T0) d0[i] = (f16)s0[i];
    else if (i < T1) d1[i - T0] = (f16)s1[i - T0];
    else if (i < T2) d2[i - T1] = (f16)s2[i - T1];
    else if (i < T3) d3[i - T2] = (f16)s3[i - T2];
}

__global__ __launch_bounds__(256) void transpose_cast2_kernel(
    const float* __restrict__ in0, f16* __restrict__ out0,
    const float* __restrict__ in1, f16* __restrict__ out1)
{
    const float* in  = blockIdx.z ? in1 : in0;
    f16*        outp = blockIdx.z ? out1 : out0;
    __shared__ float tile[32][33];
    int bx = blockIdx.x * 32, by = blockIdx.y * 32;
    int tx = threadIdx.x & 31, ty = threadIdx.x >> 5;
#pragma unroll
    for (int r = 0; r < 32; r += 8)
        tile[ty + r][tx] = in[(size_t)(by + ty + r) * H_ + bx + tx];
    __syncthreads();
#pragma unroll
    for (int r = 0; r < 32; r += 8)
        outp[(size_t)(bx + ty + r) * H_ + by + tx] = (f16)tile[tx][ty + r];
}

// ---------------------------------------------------------------------------
// 128x128 MFMA GEMM (W1xe): C = A @ Bt^T, f16 out, XCD-chunked swizzle.
// 2-phase pipeline: double-buffered LDS, reg-staged, ONE barrier per K-step.
// ---------------------------------------------------------------------------
template <typename OutT>
__global__ __launch_bounds__(256) void hgemm_kernel(
    const f16* __restrict__ A, int lda,
    const f16* __restrict__ Bt, int ldb,
    OutT* __restrict__ C, int ldc, int K)
{
    __shared__ char smem[32768];   // As[2]@0/8192, Bs[2]@16384/24576

    const int tid  = threadIdx.x;
    const int lane = tid & 63;
    const int wid  = tid >> 6;
    const int wr   = wid >> 1;
    const int wc   = wid & 1;
    const int rsel = lane & 15;
    const int kb   = lane >> 4;

    int flat = blockIdx.y * gridDim.x + blockIdx.x;
    int nwg  = gridDim.x * gridDim.y;
    int cpx  = nwg >> 3;
    int nf   = (flat & 7) * cpx + (flat >> 3);
    const int n0 = (int)(nf % gridDim.x) * 128;
    const int m0 = (int)(nf / gridDim.x) * 128;

    const int strow0 = tid >> 2;          // 0..63
    const int strow1 = 64 + (tid >> 2);   // 64..127
    const int sts    = tid & 3;

    f32x4 acc[4][4];
#pragma unroll
    for (int m = 0; m < 4; ++m)
#pragma unroll
        for (int n = 0; n < 4; ++n) acc[m][n] = (f32x4)0.f;

    f16x8 rA0, rA1, rB0, rB1;
    auto GL = [&](int k0) {
        rA0 = *(const f16x8*)(A + (size_t)(m0 + strow0) * lda + k0 + sts * 8);
        rA1 = *(const f16x8*)(A + (size_t)(m0 + strow1) * lda + k0 + sts * 8);
        rB0 = *(const f16x8*)(Bt + (size_t)(n0 + strow0) * ldb + k0 + sts * 8);
        rB1 = *(const f16x8*)(Bt + (size_t)(n0 + strow1) * ldb + k0 + sts * 8);
    };
    auto LW = [&](int c) {
        f16* As_ = (f16*)(smem + c * 8192);
        f16* Bs_ = (f16*)(smem + 16384 + c * 8192);
        lds_write_row(As_, strow0, sts, rA0);
        lds_write_row(As_, strow1, sts, rA1);
        lds_write_row(Bs_, strow0, sts, rB0);
        lds_write_row(Bs_, strow1, sts, rB1);
    };

    int cur = 0;
    GL(0);
    LW(0);
    __syncthreads();

    const int nk = K / 32;
    for (int ks = 0; ks < nk; ++ks) {
        if (ks + 1 < nk) GL((ks + 1) * 32);

        char* As_ = smem + cur * 8192;
        char* Bs_ = smem + 16384 + cur * 8192;
        f16x8 af[4], bf[4];
#pragma unroll
        for (int m = 0; m < 4; ++m) {
            int row = wr * 64 + m * 16 + rsel;
            af[m] = *(const f16x8*)(As_ + row * 64 + ((kb ^ ((row >> 1) & 3)) << 4));
        }
#pragma unroll
        for (int n = 0; n < 4; ++n) {
            int row = wc * 64 + n * 16 + rsel;
            bf[n] = *(const f16x8*)(Bs_ + row * 64 + ((kb ^ ((row >> 1) & 3)) << 4));
        }
#pragma unroll
        for (int m = 0; m < 4; ++m)
#pragma unroll
            for (int n = 0; n < 4; ++n)
                acc[m][n] = __builtin_amdgcn_mfma_f32_16x16x32_f16(af[m], bf[n], acc[m][n], 0, 0, 0);

        if (ks + 1 < nk) LW(cur ^ 1);
        __syncthreads();
        cur ^= 1;
    }

#pragma unroll
    for (int m = 0; m < 4; ++m) {
        int row0 = m0 + wr * 64 + m * 16 + kb * 4;
#pragma unroll
        for (int n = 0; n < 4; ++n) {
            int col = n0 + wc * 64 + n * 16 + rsel;
#pragma unroll
            for (int r = 0; r < 4; ++r)
                C[(size_t)(row0 + r) * ldc + col] = (OutT)acc[m][n][r];
        }
    }
}

// ---------------------------------------------------------------------------
// Fused GEMM + GRU, split-K (2 wave-groups) + 2-phase pipeline per wg.
// Per wg: As[2] (2KB each) + Bs[2] (12KB each) = 28672 B; one barrier/K-step.
// ---------------------------------------------------------------------------
template <int MODE>
__global__ __launch_bounds__(512) void gru_fused_kernel(
    const f16* __restrict__ A1, int lda1,
    const f16* __restrict__ Bt1, int ldb1, int K1,
    const f16* __restrict__ A2,
    const f16* __restrict__ Bt2,
    const float* __restrict__ bih, const float* __restrict__ bhh,
    float* __restrict__ h,
    const float* __restrict__ tg_cur,
    const float* __restrict__ tg_next,
    f16* __restrict__ out_a,
    f16* __restrict__ hs)
{
    __shared__ char smem[57344];

    const int tid  = threadIdx.x;
    const int wg   = tid >> 8;
    const int ltid = tid & 255;
    const int lane = tid & 63;
    const int wid4 = (ltid >> 6);
    const int wr   = wid4 >> 1;
    const int wc   = wid4 & 1;
    const int rsel = lane & 15;
    const int kb   = lane >> 4;

    char* base = smem + wg * 28672;   // As[c]@ c*2048, Bs[c]@ 4096 + c*12288

    int flat = blockIdx.y * gridDim.x + blockIdx.x;
    int nf   = (flat & 7) * 64 + (flat >> 3);
    const int j0 = (nf >> 5) * 64;
    const int b0 = (nf & 31) * 32;

    const int strow = ltid >> 2;   // 0..63 (A uses 0..31 via ltid<128)
    const int sts   = ltid & 3;

    f32x4 acc1[3][2], acc2[3][2];
#pragma unroll
    for (int g = 0; g < 3; ++g)
#pragma unroll
        for (int nt = 0; nt < 2; ++nt) { acc1[g][nt] = (f32x4)0.f; acc2[g][nt] = (f32x4)0.f; }

    f16x8 rA, rB[3];
    auto GL = [&](const f16* Ap, int ldap, const f16* Btp, int ldbp, int k0) {
        if (ltid < 128) rA = *(const f16x8*)(Ap + (size_t)(b0 + strow) * ldap + k0 + sts * 8);
#pragma unroll
        for (int gg = 0; gg < 3; ++gg)
            rB[gg] = *(const f16x8*)(Btp + (size_t)(gg * H_ + j0 + strow) * ldbp + k0 + sts * 8);
    };
    auto LW = [&](int c) {
        if (ltid < 128) lds_write_row((f16*)(base + c * 2048), strow, sts, rA);
        f16* Bs_ = (f16*)(base + 4096 + c * 12288);
#pragma unroll
        for (int gg = 0; gg < 3; ++gg)
            lds_write_row(Bs_ + gg * 64 * 32, strow, sts, rB[gg]);
    };

    int cur = 0;
#pragma unroll
    for (int phase = 0; phase < 2; ++phase) {
        const f16* Ap   = phase ? A2 : A1;
        const f16* Btp  = phase ? Bt2 : Bt1;
        const int  ldap = phase ? H_ : lda1;
        const int  ldbp = phase ? H_ : ldb1;
        const int  Kp   = phase ? H_ : K1;
        const int  half = Kp >> 1;
        const int  kbeg = wg * half;
        const int  nk   = half >> 5;

        GL(Ap, ldap, Btp, ldbp, kbeg);
        LW(cur);
        __syncthreads();

        for (int ks = 0; ks < nk; ++ks) {
            if (ks + 1 < nk) GL(Ap, ldap, Btp, ldbp, kbeg + (ks + 1) * 32);

            char* As_ = base + cur * 2048;
            char* Bs_ = base + 4096 + cur * 12288;
            int arow = wr * 16 + rsel;
            f16x8 af = *(const f16x8*)(As_ + arow * 64 + ((kb ^ ((arow >> 1) & 3)) << 4));
            if (phase == 0) {
#pragma unroll
                for (int gg = 0; gg < 3; ++gg)
#pragma unroll
                    for (int nt = 0; nt < 2; ++nt) {
                        int brow = wc * 32 + nt * 16 + rsel;
                        f16x8 bf = *(const f16x8*)(Bs_ + (gg * 64 + brow) * 64 +
                                                   ((kb ^ ((brow >> 1) & 3)) << 4));
                        acc1[gg][nt] = __builtin_amdgcn_mfma_f32_16x16x32_f16(af, bf, acc1[gg][nt], 0, 0, 0);
                    }
            } else {
#pragma unroll
                for (int gg = 0; gg < 3; ++gg)
#pragma unroll
                    for (int nt = 0; nt < 2; ++nt) {
                        int brow = wc * 32 + nt * 16 + rsel;
                        f16x8 bf = *(const f16x8*)(Bs_ + (gg * 64 + brow) * 64 +
                                                   ((kb ^ ((brow >> 1) & 3)) << 4));
                        acc2[gg][nt] = __builtin_amdgcn_mfma_f32_16x16x32_f16(af, bf, acc2[gg][nt], 0, 0, 0);
                    }
            }

            if (ks + 1 < nk) LW(cur ^ 1);
            __syncthreads();
            cur ^= 1;
        }
    }

    // ---- merge wave-group partials (red aliases stage smem; barrier-safe) ----
    f32x4* red = (f32x4*)smem;
    if (wg) {
#pragma unroll
        for (int g = 0; g < 3; ++g)
#pragma unroll
            for (int nt = 0; nt < 2; ++nt) red[ltid * 6 + g * 2 + nt] = acc1[g][nt];
    }
    __syncthreads();
    if (!wg) {
#pragma unroll
        for (int g = 0; g < 3; ++g)
#pragma unroll
            for (int nt = 0; nt < 2; ++nt) acc1[g][nt] += red[ltid * 6 + g * 2 + nt];
    }
    __syncthreads();
    if (wg) {
#pragma unroll
        for (int g = 0; g < 3; ++g)
#pragma unroll
            for (int nt = 0; nt < 2; ++nt) red[ltid * 6 + g * 2 + nt] = acc2[g][nt];
    }
    __syncthreads();

    if (!wg) {
#pragma unroll
        for (int g = 0; g < 3; ++g)
#pragma unroll
            for (int nt = 0; nt < 2; ++nt) acc2[g][nt] += red[ltid * 6 + g * 2 + nt];

#pragma unroll
        for (int nt = 0; nt < 2; ++nt) {
            int j = j0 + wc * 32 + nt * 16 + rsel;
            float br_i = bih[j],          br_h = bhh[j];
            float bz_i = bih[H_ + j],     bz_h = bhh[H_ + j];
            float bg_i = bih[2 * H_ + j], bg_h = bhh[2 * H_ + j];
#pragma unroll
            for (int q = 0; q < 4; ++q) {
                int row = b0 + wr * 16 + kb * 4 + q;
                float r = sigmoidf_(acc1[0][nt][q] + br_i + acc2[0][nt][q] + br_h);
                float z = sigmoidf_(acc1[1][nt][q] + bz_i + acc2[1][nt][q] + bz_h);
                float g = tanhf(acc1[2][nt][q] + bg_i + r * (acc2[2][nt][q] + bg_h));
                float leak;
                if (MODE == 0) leak = tg_cur[row] * h[(size_t)row * H_ + j];
                else           leak = h[(size_t)row * H_ + j];
                float hn = (1.f - z) * g + z * leak;
                h[(size_t)row * H_ + j] = hn;
                if (MODE == 0) {
                    out_a[(size_t)row * (N_ * H_) + j] = (f16)hn;
                    hs[(size_t)row * H_ + j] = (f16)(tg_next[row] * hn);
                } else {
                    out_a[(size_t)row * H_ + j] = (f16)hn;
                }
            }
        }
    }
}

// ---------------------------------------------------------------------------
// hw2 = h @ W2 (1024^3): split-K (2 wg) + 2-phase pipeline. 64x64 tile, f32 out.
// ---------------------------------------------------------------------------
__global__ __launch_bounds__(512) void hgemm64_kernel(
    const f16* __restrict__ A, const f16* __restrict__ Bt, float* __restrict__ C)
{
    __shared__ char smem[32768];

    const int tid  = threadIdx.x;
    const int wg   = tid >> 8;
    const int ltid = tid & 255;
    const int lane = tid & 63;
    const int wid4 = (ltid >> 6);
    const int wr   = wid4 >> 1;
    const int wc   = wid4 & 1;
    const int rsel = lane & 15;
    const int kb   = lane >> 4;

    char* base = smem + wg * 16384;   // As[c]@ c*4096, Bs[c]@ 8192 + c*4096

    int flat = blockIdx.y * gridDim.x + blockIdx.x;
    int nf   = (flat & 7) * 32 + (flat >> 3);
    const int m0 = (nf >> 4) * 64;
    const int n0 = (nf & 15) * 64;

    const int strow = ltid >> 2;
    const int sts   = ltid & 3;

    f32x4 acc[2][2];
#pragma unroll
    for (int m = 0; m < 2; ++m)
#pragma unroll
        for (int n = 0; n < 2; ++n) acc[m][n] = (f32x4)0.f;

    f16x8 rA, rB;
    auto GL = [&](int k0) {
        rA = *(const f16x8*)(A + (size_t)(m0 + strow) * H_ + k0 + sts * 8);
        rB = *(const f16x8*)(Bt + (size_t)(n0 + strow) * H_ + k0 + sts * 8);
    };
    auto LW = [&](int c) {
        lds_write_row((f16*)(base + c * 4096), strow, sts, rA);
        lds_write_row((f16*)(base + 8192 + c * 4096), strow, sts, rB);
    };

    int cur = 0;
    const int kbeg = wg * 512;
    GL(kbeg);
    LW(0);
    __syncthreads();

    for (int ks = 0; ks < 16; ++ks) {
        if (ks + 1 < 16) GL(kbeg + (ks + 1) * 32);

        char* As_ = base + cur * 4096;
        char* Bs_ = base + 8192 + cur * 4096;
        f16x8 af[2], bf[2];
#pragma unroll
        for (int m = 0; m < 2; ++m) {
            int row = wr * 32 + m * 16 + rsel;
            af[m] = *(const f16x8*)(As_ + row * 64 + ((kb ^ ((row >> 1) & 3)) << 4));
        }
#pragma unroll
        for (int nt = 0; nt < 2; ++nt) {
            int row = wc * 32 + nt * 16 + rsel;
            bf[nt] = *(const f16x8*)(Bs_ + row * 64 + ((kb ^ ((row >> 1) & 3)) << 4));
        }
#pragma unroll
        for (int m = 0; m < 2; ++m)
#pragma unroll
            for (int nt = 0; nt < 2; ++nt)
                acc[m][nt] = __builtin_amdgcn_mfma_f32_16x16x32_f16(af[m], bf[nt], acc[m][nt], 0, 0, 0);

        if (ks + 1 < 16) LW(cur ^ 1);
        __syncthreads();
        cur ^= 1;
    }

    f32x4* red = (f32x4*)smem;
    if (wg) {
#pragma unroll
        for (int m = 0; m < 2; ++m)
#pragma unroll
            for (int nt = 0; nt < 2; ++nt) red[ltid * 4 + m * 2 + nt] = acc[m][nt];
    }
    __syncthreads();
    if (!wg) {
#pragma unroll
        for (int m = 0; m < 2; ++m)
#pragma unroll
            for (int nt = 0; nt < 2; ++nt) {
                acc[m][nt] += red[ltid * 4 + m * 2 + nt];
                int col = n0 + wc * 32 + nt * 16 + rsel;
#pragma unroll
                for (int q = 0; q < 4; ++q) {
                    int row = m0 + wr * 32 + m * 16 + kb * 4 + q;
                    C[(size_t)row * H_ + col] = acc[m][nt][q];
                }
            }
    }
}

// ---------------------------------------------------------------------------
// Decoder init
// ---------------------------------------------------------------------------
__global__ void dec_init_kernel(float* __restrict__ h, f16* __restrict__ hs,
                                const f16* __restrict__ he, const int* __restrict__ idx)
{
    int i = blockIdx.x * blockDim.x + threadIdx.x;
    int b = i >> 10;
    int j = i & (H_ - 1);
    float v0 = (float)he[(size_t)b * N_ * H_ + (size_t)idx[b * N_] * H_ + j];
    h[i]  = v0;
    hs[i] = (f16)v0;
}

__global__ void init_input_kernel(f16* __restrict__ inp, const float* __restrict__ tok)
{
    int i = blockIdx.x * blockDim.x + threadIdx.x;
    inp[i] = (f16)tok[i & (I_ - 1)];
}

// ---------------------------------------------------------------------------
// Attention (+ next-step mix). One block per b, 256 threads.
// Conflict-free LDS: element k = c*64+j stored at [c*68 + j].
// ---------------------------------------------------------------------------
template <int MIX>
__global__ __launch_bounds__(256) void attn_kernel(
    const f16*   __restrict__ w1xe,
    const float* __restrict__ hw2,
    const float* __restrict__ v,
    const float* __restrict__ phis,
    const f16*   __restrict__ in16,
    float* __restrict__ out,
    f16*   __restrict__ inp_step,
    int t,
    const float* __restrict__ tg_next,
    const int*   __restrict__ idx_next,
    const f16*   __restrict__ he,
    float* __restrict__ h,
    f16*   __restrict__ hs,
    const float* __restrict__ tok)
{
    int b   = blockIdx.x;
    int tid = threadIdx.x;
    __shared__ float hw2s[16 * 68];
    __shared__ float vs[16 * 68];
    __shared__ float un[N_];
    __shared__ float attns[N_];

    {
        int k = tid * 4;
        int c = k >> 6, j = k & 63;
        float4 hv = *(const float4*)(hw2 + (size_t)b * H_ + k);
        float4 vv = *(const float4*)(v + k);
        *(float4*)&hw2s[c * 68 + j] = hv;
        *(float4*)&vs[c * 68 + j]   = vv;
    }
    __syncthreads();

    {
        int n = tid >> 4, c = tid & 15;
        const f16* wrow = w1xe + ((size_t)(b * N_ + n)) * H_ + c * 64;
        const float* hrow = &hw2s[c * 68];
        const float* vrow = &vs[c * 68];
        float s = 0.f;
#pragma unroll
        for (int u8 = 0; u8 < 8; ++u8) {
            f16x8 wv = *(const f16x8*)(wrow + u8 * 8);
            f32x4 h0 = *(const f32x4*)(hrow + u8 * 8);
            f32x4 h1 = *(const f32x4*)(hrow + u8 * 8 + 4);
            f32x4 v0 = *(const f32x4*)(vrow + u8 * 8);
            f32x4 v1 = *(const f32x4*)(vrow + u8 * 8 + 4);
#pragma unroll
            for (int e = 0; e < 4; ++e) {
                s += tanhf((float)wv[e] + h0[e]) * v0[e];
                s += tanhf((float)wv[e + 4] + h1[e]) * v1[e];
            }
        }
#pragma unroll
        for (int off = 8; off; off >>= 1) s += __shfl_down(s, off, 16);
        if (c == 0) un[n] = s;
    }
    __syncthreads();

    if (tid < N_) {
        float mk = phis[(size_t)b * N_ * N_ + t * N_ + tid];
        float um = un[tid] * mk;
        float m = um;
#pragma unroll
        for (int off = 1; off < 16; off <<= 1) m = fmaxf(m, __shfl_xor(m, off, 16));
        float e = expf(um - m) * mk;
        float ssum = e;
#pragma unroll
        for (int off = 1; off < 16; off <<= 1) ssum += __shfl_xor(ssum, off, 16);
        float a = e / ssum;
        attns[tid] = a;
        out[(size_t)b * N_ * N_ + t * N_ + tid] = a;
    }
    __syncthreads();

    float acc = 0.f;
#pragma unroll
    for (int n = 0; n < N_; ++n)
        acc += attns[n] * (float)in16[((size_t)b * N_ + n) * I_ + tid];

    if (MIX) {
        float tn = tg_next[b];
        inp_step[(size_t)b * I_ + tid] = (f16)(tn * acc + (1.f - tn) * tok[tid]);
        int id = idx_next[b * N_];
        int j4 = tid * 4;
        f16x4 ihv = *(const f16x4*)(he + (size_t)b * N_ * H_ + (size_t)id * H_ + j4);
        float4 hv = *(float4*)(h + (size_t)b * H_ + j4);
        float4 hm;
        f16x4 hsv;
#pragma unroll
        for (int e = 0; e < 4; ++e) {
            float x = tn * (&hv.x)[e] + (1.f - tn) * (float)ihv[e];
            (&hm.x)[e] = x;
            hsv[e] = (f16)x;
        }
        *(float4*)(h + (size_t)b * H_ + j4) = hm;
        *(f16x4*)(hs + (size_t)b * H_ + j4) = hsv;
    } else {
        inp_step[(size_t)b * I_ + tid] = (f16)acc;
    }
}

// ---------------------------------------------------------------------------
// Launcher
// ---------------------------------------------------------------------------
extern "C" void kernel_launch(void* const* d_in, const int* in_sizes, int n_in,
                              void* d_out, int out_size, void* d_ws, size_t ws_size,
                              hipStream_t stream)
{
    const float* input      = (const float*)d_in[0];
    const float* phis       = (const float*)d_in[1];
    const float* init_token = (const float*)d_in[2];
    const float* W1         = (const float*)d_in[3];
    const float* W2         = (const float*)d_in[4];
    const float* v          = (const float*)d_in[5];
    const float* Wih_e      = (const float*)d_in[6];
    const float* Whh_e      = (const float*)d_in[7];
    const float* bih_e      = (const float*)d_in[8];
    const float* bhh_e      = (const float*)d_in[9];
    const float* Wih_d      = (const float*)d_in[10];
    const float* Whh_d      = (const float*)d_in[11];
    const float* bih_d      = (const float*)d_in[12];
    const float* bhh_d      = (const float*)d_in[13];
    float* out = (float*)d_out;

    char* p = (char*)d_ws;
    f16*  he16    = (f16*)p;  p += (size_t)B_ * N_ * H_ * 2;
    f16*  w1xe16  = (f16*)p;  p += (size_t)B_ * N_ * H_ * 2;
    float* h      = (float*)p; p += (size_t)B_ * H_ * 4;
    f16*  hs16    = (f16*)p;  p += (size_t)B_ * H_ * 2;
    f16*  hc16    = (f16*)p;  p += (size_t)B_ * H_ * 2;
    f16*  inp16   = (f16*)p;  p += (size_t)B_ * I_ * 2;
    float* hw2    = (float*)p; p += (size_t)B_ * H_ * 4;
    f16*  in16    = (f16*)p;  p += (size_t)B_ * N_ * I_ * 2;
    f16*  Wih_e16 = (f16*)p;  p += (size_t)H3_ * I_ * 2;
    f16*  Whh_e16 = (f16*)p;  p += (size_t)H3_ * H_ * 2;
    f16*  Wih_d16 = (f16*)p;  p += (size_t)H3_ * I_ * 2;
    f16*  Whh_d16 = (f16*)p;  p += (size_t)H3_ * H_ * 2;
    f16*  W1t16   = (f16*)p;  p += (size_t)H_ * H_ * 2;
    f16*  W2t16   = (f16*)p;  p += (size_t)H_ * H_ * 2;
    float* tg     = (float*)p; p += (size_t)17 * B_ * 4;
    int*   idx    = (int*)p;   p += (size_t)B_ * N_ * 4;

    const int BHBLK = (B_ * H_) / 256;
    const int BIBLK = (B_ * I_) / 256;
    const dim3 gru_grid(16, 32);

    precompute_kernel<<<4, 256, 0, stream>>>(phis, tg, idx);

    cast_kernel<<<(B_ * N_ * I_) / 256, 256, 0, stream>>>(input, in16, B_ * N_ * I_);
    cast4_kernel<<<(2 * (H3_ * I_ + H3_ * H_)) / 256, 256, 0, stream>>>(
        Wih_e, Wih_e16, H3_ * I_, Whh_e, Whh_e16, H3_ * H_,
        Wih_d, Wih_d16, H3_ * I_, Whh_d, Whh_d16, H3_ * H_);
    transpose_cast2_kernel<<<dim3(32, 32, 2), 256, 0, stream>>>(W1, W1t16, W2, W2t16);

    // ---------------- encoder ----------------
    hipMemsetAsync(h, 0, (size_t)B_ * H_ * 4, stream);
    hipMemsetAsync(hs16, 0, (size_t)B_ * H_ * 2, stream);
    for (int t = 0; t < N_; ++t) {
        gru_fused_kernel<0><<<gru_grid, 512, 0, stream>>>(
            in16 + (size_t)t * I_, N_ * I_, Wih_e16, I_, I_,
            hs16, Whh_e16, bih_e, bhh_e, h,
            tg + (size_t)t * B_, tg + (size_t)(t + 1) * B_,
            he16 + (size_t)t * H_, hs16);
    }

    // ---------------- W1xe = he @ W1 (f16 out) ----------------
    hgemm_kernel<f16><<<dim3(H_ / 128, (B_ * N_) / 128), 256, 0, stream>>>(
        he16, H_, W1t16, H_, w1xe16, H_, H_);

    // ---------------- decoder ----------------
    dec_init_kernel<<<BHBLK, 256, 0, stream>>>(h, hs16, he16, idx);
    init_input_kernel<<<BIBLK, 256, 0, stream>>>(inp16, init_token);
    for (int t = 0; t < N_; ++t) {
        gru_fused_kernel<1><<<gru_grid, 512, 0, stream>>>(
            inp16, I_, Wih_d16, I_, I_,
            hs16, Whh_d16, bih_d, bhh_d, h,
            nullptr, nullptr, hc16, nullptr);
        hgemm64_kernel<<<dim3(16, 16), 512, 0, stream>>>(hc16, W2t16, hw2);
        if (t < N_ - 1)
            attn_kernel<1><<<B_, 256, 0, stream>>>(
                w1xe16, hw2, v, phis, in16, out, inp16, t,
                tg + (size_t)(t + 1) * B_, idx + (t + 1), he16, h, hs16, init_token);
        else
            attn_kernel<0><<<B_, 256, 0, stream>>>(
                w1xe16, hw2, v, phis, in16, out, inp16, t,
                tg, idx, he16, h, hs16, init_token);
    }
}

// Round 8
// 1341.330 us; speedup vs baseline: 4.6296x; 1.1175x over previous
//
#include <hip/hip_runtime.h>
#include <math.h>

#define B_  1024
#define N_  16
#define I_  256
#define H_  1024
#define H3_ 3072

typedef _Float16 f16;
typedef _Float16 f16x4 __attribute__((ext_vector_type(4)));
typedef _Float16 f16x8 __attribute__((ext_vector_type(8)));
typedef float    f32x4 __attribute__((ext_vector_type(4)));

__device__ __forceinline__ float sigmoidf_(float x) { return 1.f / (1.f + expf(-x)); }

// LDS layout (verified r3): row = 64B = 4 groups of 16B; group g holds
// k = {4g..4g+3, 16+4g..16+4g+3}; XOR swizzle by ((row>>1)&3).
__device__ __forceinline__ void lds_write_row(f16* dst, int row, int s, f16x8 vv)
{
    int key = (row >> 1) & 3;
    int g0  = (((s & 1) * 2 + 0) ^ key);
    int g1  = (((s & 1) * 2 + 1) ^ key);
    f16x4 lo = {vv[0], vv[1], vv[2], vv[3]};
    f16x4 hi = {vv[4], vv[5], vv[6], vv[7]};
    *(f16x4*)((char*)dst + row * 64 + g0 * 16 + (s >> 1) * 8) = lo;
    *(f16x4*)((char*)dst + row * 64 + g1 * 16 + (s >> 1) * 8) = hi;
}

// ---------------------------------------------------------------------------
// Precompute t_gate (17,B) and idx_seq (B,N)
// ---------------------------------------------------------------------------
__global__ void precompute_kernel(const float* __restrict__ phis,
                                  float* __restrict__ tg,
                                  int* __restrict__ idx)
{
    int b = blockIdx.x * blockDim.x + threadIdx.x;
    if (b >= B_) return;
    tg[b] = 1.0f;
    for (int t = 1; t < N_; ++t)
        tg[t * B_ + b] = phis[(size_t)b * N_ * N_ + t * N_ + (t - 1)];
    tg[16 * B_ + b] = 0.0f;
    for (int t = 0; t < N_; ++t) {
        float ns = 0.f;
        for (int k = 0; k < N_; ++k) ns += phis[(size_t)b * N_ * N_ + t * N_ + k];
        int nsi = (int)(ns + 0.5f);
        idx[b * N_ + t] = (nsi + t - 1) % N_;
    }
}

// ---------------------------------------------------------------------------
// Casts
// ---------------------------------------------------------------------------
__global__ void cast_kernel(const float* __restrict__ in, f16* __restrict__ out, int n)
{
    int i = blockIdx.x * blockDim.x + threadIdx.x;
    if (i < n) out[i] = (f16)in[i];
}

__global__ void cast4_kernel(const float* __restrict__ s0, f16* __restrict__ d0, int n0,
                             const float* __restrict__ s1, f16* __restrict__ d1, int n1,
                             const float* __restrict__ s2, f16* __restrict__ d2, int n2,
                             const float* __restrict__ s3, f16* __restrict__ d3, int n3)
{
    int i = blockIdx.x * blockDim.x + threadIdx.x;
    int T0 = n0, T1 = T0 + n1, T2 = T1 + n2, T3 = T2 + n3;
    if (i < T0) d0[i] = (f16)s0[i];
    else if (i < T1) d1[i - T0] = (f16)s1[i - T0];
    else if (i < T2) d2[i - T1] = (f16)s2[i - T1];
    else if (i < T3) d3[i - T2] = (f16)s3[i - T2];
}

__global__ __launch_bounds__(256) void transpose_cast2_kernel(
    const float* __restrict__ in0, f16* __restrict__ out0,
    const float* __restrict__ in1, f16* __restrict__ out1)
{
    const float* in  = blockIdx.z ? in1 : in0;
    f16*        outp = blockIdx.z ? out1 : out0;
    __shared__ float tile[32][33];
    int bx = blockIdx.x * 32, by = blockIdx.y * 32;
    int tx = threadIdx.x & 31, ty = threadIdx.x >> 5;
#pragma unroll
    for (int r = 0; r < 32; r += 8)
        tile[ty + r][tx] = in[(size_t)(by + ty + r) * H_ + bx + tx];
    __syncthreads();
#pragma unroll
    for (int r = 0; r < 32; r += 8)
        outp[(size_t)(bx + ty + r) * H_ + by + tx] = (f16)tile[tx][ty + r];
}

// ---------------------------------------------------------------------------
// 128x128 MFMA GEMM (W1xe): C = A @ Bt^T, f16 out, XCD-chunked swizzle.
// 2-phase pipeline: double-buffered LDS, reg-staged, ONE barrier per K-step.
// ---------------------------------------------------------------------------
template <typename OutT>
__global__ __launch_bounds__(256) void hgemm_kernel(
    const f16* __restrict__ A, int lda,
    const f16* __restrict__ Bt, int ldb,
    OutT* __restrict__ C, int ldc, int K)
{
    __shared__ char smem[32768];   // As[2]@0/8192, Bs[2]@16384/24576

    const int tid  = threadIdx.x;
    const int lane = tid & 63;
    const int wid  = tid >> 6;
    const int wr   = wid >> 1;
    const int wc   = wid & 1;
    const int rsel = lane & 15;
    const int kb   = lane >> 4;

    int flat = blockIdx.y * gridDim.x + blockIdx.x;
    int nwg  = gridDim.x * gridDim.y;
    int cpx  = nwg >> 3;
    int nf   = (flat & 7) * cpx + (flat >> 3);
    const int n0 = (int)(nf % gridDim.x) * 128;
    const int m0 = (int)(nf / gridDim.x) * 128;

    const int strow0 = tid >> 2;
    const int strow1 = 64 + (tid >> 2);
    const int sts    = tid & 3;

    f32x4 acc[4][4];
#pragma unroll
    for (int m = 0; m < 4; ++m)
#pragma unroll
        for (int n = 0; n < 4; ++n) acc[m][n] = (f32x4)0.f;

    f16x8 rA0, rA1, rB0, rB1;
    auto GL = [&](int k0) {
        rA0 = *(const f16x8*)(A + (size_t)(m0 + strow0) * lda + k0 + sts * 8);
        rA1 = *(const f16x8*)(A + (size_t)(m0 + strow1) * lda + k0 + sts * 8);
        rB0 = *(const f16x8*)(Bt + (size_t)(n0 + strow0) * ldb + k0 + sts * 8);
        rB1 = *(const f16x8*)(Bt + (size_t)(n0 + strow1) * ldb + k0 + sts * 8);
    };
    auto LW = [&](int c) {
        f16* As_ = (f16*)(smem + c * 8192);
        f16* Bs_ = (f16*)(smem + 16384 + c * 8192);
        lds_write_row(As_, strow0, sts, rA0);
        lds_write_row(As_, strow1, sts, rA1);
        lds_write_row(Bs_, strow0, sts, rB0);
        lds_write_row(Bs_, strow1, sts, rB1);
    };

    int cur = 0;
    GL(0);
    LW(0);
    __syncthreads();

    const int nk = K / 32;
    for (int ks = 0; ks < nk; ++ks) {
        if (ks + 1 < nk) GL((ks + 1) * 32);

        char* As_ = smem + cur * 8192;
        char* Bs_ = smem + 16384 + cur * 8192;
        f16x8 af[4], bf[4];
#pragma unroll
        for (int m = 0; m < 4; ++m) {
            int row = wr * 64 + m * 16 + rsel;
            af[m] = *(const f16x8*)(As_ + row * 64 + ((kb ^ ((row >> 1) & 3)) << 4));
        }
#pragma unroll
        for (int n = 0; n < 4; ++n) {
            int row = wc * 64 + n * 16 + rsel;
            bf[n] = *(const f16x8*)(Bs_ + row * 64 + ((kb ^ ((row >> 1) & 3)) << 4));
        }
#pragma unroll
        for (int m = 0; m < 4; ++m)
#pragma unroll
            for (int n = 0; n < 4; ++n)
                acc[m][n] = __builtin_amdgcn_mfma_f32_16x16x32_f16(af[m], bf[n], acc[m][n], 0, 0, 0);

        if (ks + 1 < nk) LW(cur ^ 1);
        __syncthreads();
        cur ^= 1;
    }

#pragma unroll
    for (int m = 0; m < 4; ++m) {
        int row0 = m0 + wr * 64 + m * 16 + kb * 4;
#pragma unroll
        for (int n = 0; n < 4; ++n) {
            int col = n0 + wc * 64 + n * 16 + rsel;
#pragma unroll
            for (int r = 0; r < 4; ++r)
                C[(size_t)(row0 + r) * ldc + col] = (OutT)acc[m][n][r];
        }
    }
}

// ---------------------------------------------------------------------------
// Fused GEMM + GRU, split-K (2 wave-groups) + 2-phase pipeline per wg.
// ---------------------------------------------------------------------------
template <int MODE>
__global__ __launch_bounds__(512) void gru_fused_kernel(
    const f16* __restrict__ A1, int lda1,
    const f16* __restrict__ Bt1, int ldb1, int K1,
    const f16* __restrict__ A2,
    const f16* __restrict__ Bt2,
    const float* __restrict__ bih, const float* __restrict__ bhh,
    float* __restrict__ h,
    const float* __restrict__ tg_cur,
    const float* __restrict__ tg_next,
    f16* __restrict__ out_a,
    f16* __restrict__ hs)
{
    __shared__ char smem[57344];

    const int tid  = threadIdx.x;
    const int wg   = tid >> 8;
    const int ltid = tid & 255;
    const int lane = tid & 63;
    const int wid4 = (ltid >> 6);
    const int wr   = wid4 >> 1;
    const int wc   = wid4 & 1;
    const int rsel = lane & 15;
    const int kb   = lane >> 4;

    char* base = smem + wg * 28672;

    int flat = blockIdx.y * gridDim.x + blockIdx.x;
    int nf   = (flat & 7) * 64 + (flat >> 3);
    const int j0 = (nf >> 5) * 64;
    const int b0 = (nf & 31) * 32;

    const int strow = ltid >> 2;
    const int sts   = ltid & 3;

    f32x4 acc1[3][2], acc2[3][2];
#pragma unroll
    for (int g = 0; g < 3; ++g)
#pragma unroll
        for (int nt = 0; nt < 2; ++nt) { acc1[g][nt] = (f32x4)0.f; acc2[g][nt] = (f32x4)0.f; }

    f16x8 rA, rB[3];
    auto GL = [&](const f16* Ap, int ldap, const f16* Btp, int ldbp, int k0) {
        if (ltid < 128) rA = *(const f16x8*)(Ap + (size_t)(b0 + strow) * ldap + k0 + sts * 8);
#pragma unroll
        for (int gg = 0; gg < 3; ++gg)
            rB[gg] = *(const f16x8*)(Btp + (size_t)(gg * H_ + j0 + strow) * ldbp + k0 + sts * 8);
    };
    auto LW = [&](int c) {
        if (ltid < 128) lds_write_row((f16*)(base + c * 2048), strow, sts, rA);
        f16* Bs_ = (f16*)(base + 4096 + c * 12288);
#pragma unroll
        for (int gg = 0; gg < 3; ++gg)
            lds_write_row(Bs_ + gg * 64 * 32, strow, sts, rB[gg]);
    };

    int cur = 0;
#pragma unroll
    for (int phase = 0; phase < 2; ++phase) {
        const f16* Ap   = phase ? A2 : A1;
        const f16* Btp  = phase ? Bt2 : Bt1;
        const int  ldap = phase ? H_ : lda1;
        const int  ldbp = phase ? H_ : ldb1;
        const int  Kp   = phase ? H_ : K1;
        const int  half = Kp >> 1;
        const int  kbeg = wg * half;
        const int  nk   = half >> 5;

        GL(Ap, ldap, Btp, ldbp, kbeg);
        LW(cur);
        __syncthreads();

        for (int ks = 0; ks < nk; ++ks) {
            if (ks + 1 < nk) GL(Ap, ldap, Btp, ldbp, kbeg + (ks + 1) * 32);

            char* As_ = base + cur * 2048;
            char* Bs_ = base + 4096 + cur * 12288;
            int arow = wr * 16 + rsel;
            f16x8 af = *(const f16x8*)(As_ + arow * 64 + ((kb ^ ((arow >> 1) & 3)) << 4));
            if (phase == 0) {
#pragma unroll
                for (int gg = 0; gg < 3; ++gg)
#pragma unroll
                    for (int nt = 0; nt < 2; ++nt) {
                        int brow = wc * 32 + nt * 16 + rsel;
                        f16x8 bf = *(const f16x8*)(Bs_ + (gg * 64 + brow) * 64 +
                                                   ((kb ^ ((brow >> 1) & 3)) << 4));
                        acc1[gg][nt] = __builtin_amdgcn_mfma_f32_16x16x32_f16(af, bf, acc1[gg][nt], 0, 0, 0);
                    }
            } else {
#pragma unroll
                for (int gg = 0; gg < 3; ++gg)
#pragma unroll
                    for (int nt = 0; nt < 2; ++nt) {
                        int brow = wc * 32 + nt * 16 + rsel;
                        f16x8 bf = *(const f16x8*)(Bs_ + (gg * 64 + brow) * 64 +
                                                   ((kb ^ ((brow >> 1) & 3)) << 4));
                        acc2[gg][nt] = __builtin_amdgcn_mfma_f32_16x16x32_f16(af, bf, acc2[gg][nt], 0, 0, 0);
                    }
            }

            if (ks + 1 < nk) LW(cur ^ 1);
            __syncthreads();
            cur ^= 1;
        }
    }

    f32x4* red = (f32x4*)smem;
    if (wg) {
#pragma unroll
        for (int g = 0; g < 3; ++g)
#pragma unroll
            for (int nt = 0; nt < 2; ++nt) red[ltid * 6 + g * 2 + nt] = acc1[g][nt];
    }
    __syncthreads();
    if (!wg) {
#pragma unroll
        for (int g = 0; g < 3; ++g)
#pragma unroll
            for (int nt = 0; nt < 2; ++nt) acc1[g][nt] += red[ltid * 6 + g * 2 + nt];
    }
    __syncthreads();
    if (wg) {
#pragma unroll
        for (int g = 0; g < 3; ++g)
#pragma unroll
            for (int nt = 0; nt < 2; ++nt) red[ltid * 6 + g * 2 + nt] = acc2[g][nt];
    }
    __syncthreads();

    if (!wg) {
#pragma unroll
        for (int g = 0; g < 3; ++g)
#pragma unroll
            for (int nt = 0; nt < 2; ++nt) acc2[g][nt] += red[ltid * 6 + g * 2 + nt];

#pragma unroll
        for (int nt = 0; nt < 2; ++nt) {
            int j = j0 + wc * 32 + nt * 16 + rsel;
            float br_i = bih[j],          br_h = bhh[j];
            float bz_i = bih[H_ + j],     bz_h = bhh[H_ + j];
            float bg_i = bih[2 * H_ + j], bg_h = bhh[2 * H_ + j];
#pragma unroll
            for (int q = 0; q < 4; ++q) {
                int row = b0 + wr * 16 + kb * 4 + q;
                float r = sigmoidf_(acc1[0][nt][q] + br_i + acc2[0][nt][q] + br_h);
                float z = sigmoidf_(acc1[1][nt][q] + bz_i + acc2[1][nt][q] + bz_h);
                float g = tanhf(acc1[2][nt][q] + bg_i + r * (acc2[2][nt][q] + bg_h));
                float leak;
                if (MODE == 0) leak = tg_cur[row] * h[(size_t)row * H_ + j];
                else           leak = h[(size_t)row * H_ + j];
                float hn = (1.f - z) * g + z * leak;
                h[(size_t)row * H_ + j] = hn;
                if (MODE == 0) {
                    out_a[(size_t)row * (N_ * H_) + j] = (f16)hn;
                    hs[(size_t)row * H_ + j] = (f16)(tg_next[row] * hn);
                } else {
                    out_a[(size_t)row * H_ + j] = (f16)hn;
                }
            }
        }
    }
}

// ---------------------------------------------------------------------------
// hw2 = h @ W2 (1024^3): split-K (2 wg) + 2-phase pipeline. 64x64 tile, f32 out.
// ---------------------------------------------------------------------------
__global__ __launch_bounds__(512) void hgemm64_kernel(
    const f16* __restrict__ A, const f16* __restrict__ Bt, float* __restrict__ C)
{
    __shared__ char smem[32768];

    const int tid  = threadIdx.x;
    const int wg   = tid >> 8;
    const int ltid = tid & 255;
    const int lane = tid & 63;
    const int wid4 = (ltid >> 6);
    const int wr   = wid4 >> 1;
    const int wc   = wid4 & 1;
    const int rsel = lane & 15;
    const int kb   = lane >> 4;

    char* base = smem + wg * 16384;

    int flat = blockIdx.y * gridDim.x + blockIdx.x;
    int nf   = (flat & 7) * 32 + (flat >> 3);
    const int m0 = (nf >> 4) * 64;
    const int n0 = (nf & 15) * 64;

    const int strow = ltid >> 2;
    const int sts   = ltid & 3;

    f32x4 acc[2][2];
#pragma unroll
    for (int m = 0; m < 2; ++m)
#pragma unroll
        for (int n = 0; n < 2; ++n) acc[m][n] = (f32x4)0.f;

    f16x8 rA, rB;
    auto GL = [&](int k0) {
        rA = *(const f16x8*)(A + (size_t)(m0 + strow) * H_ + k0 + sts * 8);
        rB = *(const f16x8*)(Bt + (size_t)(n0 + strow) * H_ + k0 + sts * 8);
    };
    auto LW = [&](int c) {
        lds_write_row((f16*)(base + c * 4096), strow, sts, rA);
        lds_write_row((f16*)(base + 8192 + c * 4096), strow, sts, rB);
    };

    int cur = 0;
    const int kbeg = wg * 512;
    GL(kbeg);
    LW(0);
    __syncthreads();

    for (int ks = 0; ks < 16; ++ks) {
        if (ks + 1 < 16) GL(kbeg + (ks + 1) * 32);

        char* As_ = base + cur * 4096;
        char* Bs_ = base + 8192 + cur * 4096;
        f16x8 af[2], bf[2];
#pragma unroll
        for (int m = 0; m < 2; ++m) {
            int row = wr * 32 + m * 16 + rsel;
            af[m] = *(const f16x8*)(As_ + row * 64 + ((kb ^ ((row >> 1) & 3)) << 4));
        }
#pragma unroll
        for (int nt = 0; nt < 2; ++nt) {
            int row = wc * 32 + nt * 16 + rsel;
            bf[nt] = *(const f16x8*)(Bs_ + row * 64 + ((kb ^ ((row >> 1) & 3)) << 4));
        }
#pragma unroll
        for (int m = 0; m < 2; ++m)
#pragma unroll
            for (int nt = 0; nt < 2; ++nt)
                acc[m][nt] = __builtin_amdgcn_mfma_f32_16x16x32_f16(af[m], bf[nt], acc[m][nt], 0, 0, 0);

        if (ks + 1 < 16) LW(cur ^ 1);
        __syncthreads();
        cur ^= 1;
    }

    f32x4* red = (f32x4*)smem;
    if (wg) {
#pragma unroll
        for (int m = 0; m < 2; ++m)
#pragma unroll
            for (int nt = 0; nt < 2; ++nt) red[ltid * 4 + m * 2 + nt] = acc[m][nt];
    }
    __syncthreads();
    if (!wg) {
#pragma unroll
        for (int m = 0; m < 2; ++m)
#pragma unroll
            for (int nt = 0; nt < 2; ++nt) {
                acc[m][nt] += red[ltid * 4 + m * 2 + nt];
                int col = n0 + wc * 32 + nt * 16 + rsel;
#pragma unroll
                for (int q = 0; q < 4; ++q) {
                    int row = m0 + wr * 32 + m * 16 + kb * 4 + q;
                    C[(size_t)row * H_ + col] = acc[m][nt][q];
                }
            }
    }
}

// ---------------------------------------------------------------------------
// Decoder init
// ---------------------------------------------------------------------------
__global__ void dec_init_kernel(float* __restrict__ h, f16* __restrict__ hs,
                                const f16* __restrict__ he, const int* __restrict__ idx)
{
    int i = blockIdx.x * blockDim.x + threadIdx.x;
    int b = i >> 10;
    int j = i & (H_ - 1);
    float v0 = (float)he[(size_t)b * N_ * H_ + (size_t)idx[b * N_] * H_ + j];
    h[i]  = v0;
    hs[i] = (f16)v0;
}

__global__ void init_input_kernel(f16* __restrict__ inp, const float* __restrict__ tok)
{
    int i = blockIdx.x * blockDim.x + threadIdx.x;
    inp[i] = (f16)tok[i & (I_ - 1)];
}

// ---------------------------------------------------------------------------
// Attention (+ next-step mix). One block per b, 1024 threads = 16 waves.
// Wave w computes u[b,w]: lane l owns k in {8l..8l+7} U {512+8l..512+8l+7},
// reads w1xe/hw2/v straight from global (no LDS, no conflicts), 16 tanh-FMAs,
// 64-lane shfl reduce. Softmax on wave 0; einsum tid<256; h-mix 1 thread/elem.
// ---------------------------------------------------------------------------
template <int MIX>
__global__ __launch_bounds__(1024) void attn_kernel(
    const f16*   __restrict__ w1xe,
    const float* __restrict__ hw2,
    const float* __restrict__ v,
    const float* __restrict__ phis,
    const f16*   __restrict__ in16,
    float* __restrict__ out,
    f16*   __restrict__ inp_step,
    int t,
    const float* __restrict__ tg_next,
    const int*   __restrict__ idx_next,
    const f16*   __restrict__ he,
    float* __restrict__ h,
    f16*   __restrict__ hs,
    const float* __restrict__ tok)
{
    int b   = blockIdx.x;
    int tid = threadIdx.x;
    int w   = tid >> 6;    // wave = n row
    int l   = tid & 63;
    __shared__ float un[N_];
    __shared__ float attns[N_];

    {
        const f16*   wrow = w1xe + ((size_t)(b * N_ + w)) * H_;
        const float* hwp  = hw2 + (size_t)b * H_;
        f16x8 w0 = *(const f16x8*)(wrow + l * 8);
        f16x8 w1 = *(const f16x8*)(wrow + 512 + l * 8);
        f32x4 h0 = *(const f32x4*)(hwp + l * 8);
        f32x4 h1 = *(const f32x4*)(hwp + l * 8 + 4);
        f32x4 h2 = *(const f32x4*)(hwp + 512 + l * 8);
        f32x4 h3 = *(const f32x4*)(hwp + 512 + l * 8 + 4);
        f32x4 v0 = *(const f32x4*)(v + l * 8);
        f32x4 v1 = *(const f32x4*)(v + l * 8 + 4);
        f32x4 v2 = *(const f32x4*)(v + 512 + l * 8);
        f32x4 v3 = *(const f32x4*)(v + 512 + l * 8 + 4);
        float s = 0.f;
#pragma unroll
        for (int e = 0; e < 4; ++e) {
            s += tanhf((float)w0[e]     + h0[e]) * v0[e];
            s += tanhf((float)w0[e + 4] + h1[e]) * v1[e];
            s += tanhf((float)w1[e]     + h2[e]) * v2[e];
            s += tanhf((float)w1[e + 4] + h3[e]) * v3[e];
        }
#pragma unroll
        for (int off = 32; off; off >>= 1) s += __shfl_down(s, off, 64);
        if (l == 0) un[w] = s;
    }
    __syncthreads();

    if (tid < N_) {
        float mk = phis[(size_t)b * N_ * N_ + t * N_ + tid];
        float um = un[tid] * mk;
        float m = um;
#pragma unroll
        for (int off = 1; off < 16; off <<= 1) m = fmaxf(m, __shfl_xor(m, off, 16));
        float e = expf(um - m) * mk;
        float ssum = e;
#pragma unroll
        for (int off = 1; off < 16; off <<= 1) ssum += __shfl_xor(ssum, off, 16);
        float a = e / ssum;
        attns[tid] = a;
        out[(size_t)b * N_ * N_ + t * N_ + tid] = a;
    }
    __syncthreads();

    if (tid < I_) {
        float acc = 0.f;
#pragma unroll
        for (int n = 0; n < N_; ++n)
            acc += attns[n] * (float)in16[((size_t)b * N_ + n) * I_ + tid];
        if (MIX) {
            float tn = tg_next[b];
            inp_step[(size_t)b * I_ + tid] = (f16)(tn * acc + (1.f - tn) * tok[tid]);
        } else {
            inp_step[(size_t)b * I_ + tid] = (f16)acc;
        }
    }

    if (MIX) {
        float tn = tg_next[b];
        int id = idx_next[b * N_];
        float ih = (float)he[(size_t)b * N_ * H_ + (size_t)id * H_ + tid];
        float hm = tn * h[(size_t)b * H_ + tid] + (1.f - tn) * ih;
        h[(size_t)b * H_ + tid]  = hm;
        hs[(size_t)b * H_ + tid] = (f16)hm;
    }
}

// ---------------------------------------------------------------------------
// Launcher
// ---------------------------------------------------------------------------
extern "C" void kernel_launch(void* const* d_in, const int* in_sizes, int n_in,
                              void* d_out, int out_size, void* d_ws, size_t ws_size,
                              hipStream_t stream)
{
    const float* input      = (const float*)d_in[0];
    const float* phis       = (const float*)d_in[1];
    const float* init_token = (const float*)d_in[2];
    const float* W1         = (const float*)d_in[3];
    const float* W2         = (const float*)d_in[4];
    const float* v          = (const float*)d_in[5];
    const float* Wih_e      = (const float*)d_in[6];
    const float* Whh_e      = (const float*)d_in[7];
    const float* bih_e      = (const float*)d_in[8];
    const float* bhh_e      = (const float*)d_in[9];
    const float* Wih_d      = (const float*)d_in[10];
    const float* Whh_d      = (const float*)d_in[11];
    const float* bih_d      = (const float*)d_in[12];
    const float* bhh_d      = (const float*)d_in[13];
    float* out = (float*)d_out;

    char* p = (char*)d_ws;
    f16*  he16    = (f16*)p;  p += (size_t)B_ * N_ * H_ * 2;
    f16*  w1xe16  = (f16*)p;  p += (size_t)B_ * N_ * H_ * 2;
    float* h      = (float*)p; p += (size_t)B_ * H_ * 4;
    f16*  hs16    = (f16*)p;  p += (size_t)B_ * H_ * 2;
    f16*  hc16    = (f16*)p;  p += (size_t)B_ * H_ * 2;
    f16*  inp16   = (f16*)p;  p += (size_t)B_ * I_ * 2;
    float* hw2    = (float*)p; p += (size_t)B_ * H_ * 4;
    f16*  in16    = (f16*)p;  p += (size_t)B_ * N_ * I_ * 2;
    f16*  Wih_e16 = (f16*)p;  p += (size_t)H3_ * I_ * 2;
    f16*  Whh_e16 = (f16*)p;  p += (size_t)H3_ * H_ * 2;
    f16*  Wih_d16 = (f16*)p;  p += (size_t)H3_ * I_ * 2;
    f16*  Whh_d16 = (f16*)p;  p += (size_t)H3_ * H_ * 2;
    f16*  W1t16   = (f16*)p;  p += (size_t)H_ * H_ * 2;
    f16*  W2t16   = (f16*)p;  p += (size_t)H_ * H_ * 2;
    float* tg     = (float*)p; p += (size_t)17 * B_ * 4;
    int*   idx    = (int*)p;   p += (size_t)B_ * N_ * 4;

    const int BHBLK = (B_ * H_) / 256;
    const int BIBLK = (B_ * I_) / 256;
    const dim3 gru_grid(16, 32);

    precompute_kernel<<<4, 256, 0, stream>>>(phis, tg, idx);

    cast_kernel<<<(B_ * N_ * I_) / 256, 256, 0, stream>>>(input, in16, B_ * N_ * I_);
    cast4_kernel<<<(2 * (H3_ * I_ + H3_ * H_)) / 256, 256, 0, stream>>>(
        Wih_e, Wih_e16, H3_ * I_, Whh_e, Whh_e16, H3_ * H_,
        Wih_d, Wih_d16, H3_ * I_, Whh_d, Whh_d16, H3_ * H_);
    transpose_cast2_kernel<<<dim3(32, 32, 2), 256, 0, stream>>>(W1, W1t16, W2, W2t16);

    // ---------------- encoder ----------------
    hipMemsetAsync(h, 0, (size_t)B_ * H_ * 4, stream);
    hipMemsetAsync(hs16, 0, (size_t)B_ * H_ * 2, stream);
    for (int t = 0; t < N_; ++t) {
        gru_fused_kernel<0><<<gru_grid, 512, 0, stream>>>(
            in16 + (size_t)t * I_, N_ * I_, Wih_e16, I_, I_,
            hs16, Whh_e16, bih_e, bhh_e, h,
            tg + (size_t)t * B_, tg + (size_t)(t + 1) * B_,
            he16 + (size_t)t * H_, hs16);
    }

    // ---------------- W1xe = he @ W1 (f16 out) ----------------
    hgemm_kernel<f16><<<dim3(H_ / 128, (B_ * N_) / 128), 256, 0, stream>>>(
        he16, H_, W1t16, H_, w1xe16, H_, H_);

    // ---------------- decoder ----------------
    dec_init_kernel<<<BHBLK, 256, 0, stream>>>(h, hs16, he16, idx);
    init_input_kernel<<<BIBLK, 256, 0, stream>>>(inp16, init_token);
    for (int t = 0; t < N_; ++t) {
        gru_fused_kernel<1><<<gru_grid, 512, 0, stream>>>(
            inp16, I_, Wih_d16, I_, I_,
            hs16, Whh_d16, bih_d, bhh_d, h,
            nullptr, nullptr, hc16, nullptr);
        hgemm64_kernel<<<dim3(16, 16), 512, 0, stream>>>(hc16, W2t16, hw2);
        if (t < N_ - 1)
            attn_kernel<1><<<B_, 1024, 0, stream>>>(
                w1xe16, hw2, v, phis, in16, out, inp16, t,
                tg + (size_t)(t + 1) * B_, idx + (t + 1), he16, h, hs16, init_token);
        else
            attn_kernel<0><<<B_, 1024, 0, stream>>>(
                w1xe16, hw2, v, phis, in16, out, inp16, t,
                tg, idx, he16, h, hs16, init_token);
    }
}